// Round 3
// baseline (2438.984 us; speedup 1.0000x reference)
//
#include <hip/hip_runtime.h>
#include <hip/hip_bf16.h>

#define H100 100
#define NPLANE 25
#define BN_EPS 1e-5f

// ================= CSR build =================
__global__ __launch_bounds__(256) void deg_int_kernel(const int* __restrict__ col,
                                                      int* __restrict__ degi, int E) {
    int t = blockIdx.x * 256 + threadIdx.x;
    if (t < E) atomicAdd(&degi[col[t]], 1);
}

__global__ __launch_bounds__(256) void scan1_kernel(const int* __restrict__ degi,
                                                    int* __restrict__ rowptr,
                                                    int* __restrict__ bsum, int n) {
    __shared__ int lds[256];
    const int t = threadIdx.x;
    const int gid = blockIdx.x * 256 + t;
    int v = (gid < n) ? degi[gid] : 0;
    lds[t] = v;
    __syncthreads();
    for (int off = 1; off < 256; off <<= 1) {
        int u = (t >= off) ? lds[t - off] : 0;
        __syncthreads();
        lds[t] += u;
        __syncthreads();
    }
    if (gid < n) rowptr[gid + 1] = lds[t];
    if (t == 255) bsum[blockIdx.x] = lds[t];
}

__global__ __launch_bounds__(1024) void scan2_kernel(int* __restrict__ bsum, int nb) {
    __shared__ int lds[1024];
    const int t = threadIdx.x;
    int v = (t < nb) ? bsum[t] : 0;
    lds[t] = v;
    __syncthreads();
    for (int off = 1; off < 1024; off <<= 1) {
        int u = (t >= off) ? lds[t - off] : 0;
        __syncthreads();
        lds[t] += u;
        __syncthreads();
    }
    if (t < nb) bsum[t] = lds[t] - v;   // exclusive
}

__global__ __launch_bounds__(256) void scan3_kernel(int* __restrict__ rowptr,
                                                    const int* __restrict__ bsum,
                                                    const int* __restrict__ degi,
                                                    float* __restrict__ dis,
                                                    int* __restrict__ cursor, int n) {
    const int gid = blockIdx.x * 256 + threadIdx.x;
    if (gid >= n) return;
    const int d = degi[gid];
    const int rp1 = rowptr[gid + 1] + bsum[blockIdx.x];
    rowptr[gid + 1] = rp1;
    cursor[gid] = rp1 - d;
    if (gid == 0) rowptr[0] = 0;
    dis[gid] = rsqrtf((float)(d + 1));
}

__global__ __launch_bounds__(256) void fill_csr_kernel(const int* __restrict__ row,
                                                       const int* __restrict__ col,
                                                       int* __restrict__ cursor,
                                                       int* __restrict__ srcidx, int E) {
    int e = blockIdx.x * 256 + threadIdx.x;
    if (e >= E) return;
    int slot = atomicAdd(&cursor[col[e]], 1);
    srcidx[slot] = row[e];
}

// ================= BN fold =================
__global__ __launch_bounds__(256) void bnprep_kernel(const float* __restrict__ b,
                                                     const float* __restrict__ gamma,
                                                     const float* __restrict__ beta,
                                                     const float* __restrict__ mean,
                                                     const float* __restrict__ var,
                                                     float* __restrict__ sarr,
                                                     float* __restrict__ tarr) {
    int idx = blockIdx.x * 256 + threadIdx.x;
    if (idx >= 4 * H100) return;
    float s = gamma[idx] * rsqrtf(var[idx] + BN_EPS);
    sarr[idx] = s;
    tarr[idx] = (b[idx] - mean[idx]) * s + beta[idx];
}

// ================= GEMM: xwp[q][i] = ((h[i] @ W)[4q..4q+3]) * dis[i] =================
// PLANAR=false: hin is node-major [n, CIN] (layer 0 input x)
// PLANAR=true : hin is plane-major float4[CIN/4][n]
template <int CIN, bool PLANAR>
__global__ __launch_bounds__(256) void gemm_scale_kernel(
    const float* __restrict__ hin, const float* __restrict__ W,
    const float* __restrict__ dis, float4* __restrict__ xwp, int n)
{
    constexpr int KH = (CIN + 1) / 2;
    __shared__ float Wl[KH * H100 + 32];
    __shared__ float hsT[CIN * 68];
    const int tid = threadIdx.x;
    const int node0 = blockIdx.x * 64;

    if (PLANAR) {
        // hin = planes: float4[CIN/4][n]; read plane q, 64 consecutive nodes (coalesced)
        const float4* __restrict__ hp = reinterpret_cast<const float4*>(hin);
        for (int idx = tid; idx < 64 * (CIN / 4); idx += 256) {
            int q = idx >> 6;
            int r = idx & 63;
            int node = node0 + r;
            float4 v = (node < n) ? hp[(size_t)q * n + node] : make_float4(0.f, 0.f, 0.f, 0.f);
            hsT[(4 * q + 0) * 68 + r] = v.x;
            hsT[(4 * q + 1) * 68 + r] = v.y;
            hsT[(4 * q + 2) * 68 + r] = v.z;
            hsT[(4 * q + 3) * 68 + r] = v.w;
        }
    } else {
        for (int idx = tid; idx < 64 * CIN; idx += 256) {
            int r = idx / CIN;
            int k = idx - r * CIN;
            int node = node0 + r;
            hsT[k * 68 + r] = (node < n) ? hin[node * CIN + k] : 0.0f;
        }
    }

    const int tx = tid & 15;
    const int ty = tid >> 4;
    float acc0[4][4] = {{0.f}};
    float acc1[4][4] = {{0.f}};

    for (int p = 0; p < 2; ++p) {
        const int k0 = p * KH;
        const int kn = (CIN - k0 < KH) ? (CIN - k0) : KH;
        __syncthreads();
        for (int idx = tid; idx < kn * H100; idx += 256)
            Wl[idx] = W[k0 * H100 + idx];
        __syncthreads();
        for (int kk = 0; kk < kn; ++kk) {
            const float4 a  = *reinterpret_cast<const float4*>(&hsT[(k0 + kk) * 68 + ty * 4]);
            const float4 w0 = *reinterpret_cast<const float4*>(&Wl[kk * H100 + tx * 4]);
            const float4 w1 = *reinterpret_cast<const float4*>(&Wl[kk * H100 + 64 + tx * 4]);
            const float av[4]  = {a.x, a.y, a.z, a.w};
            const float w0v[4] = {w0.x, w0.y, w0.z, w0.w};
            const float w1v[4] = {w1.x, w1.y, w1.z, w1.w};
            #pragma unroll
            for (int ni = 0; ni < 4; ++ni)
                #pragma unroll
                for (int ci = 0; ci < 4; ++ci) {
                    acc0[ni][ci] += av[ni] * w0v[ci];
                    acc1[ni][ci] += av[ni] * w1v[ci];
                }
        }
    }

    // thread (tx,ty): plane tx nodes node0+ty*4..+3 (64B contiguous), plus plane 16+tx (tx<9)
    #pragma unroll
    for (int ni = 0; ni < 4; ++ni) {
        const int node = node0 + ty * 4 + ni;
        if (node >= n) continue;
        const float s = dis[node];
        xwp[(size_t)tx * n + node] =
            make_float4(acc0[ni][0] * s, acc0[ni][1] * s, acc0[ni][2] * s, acc0[ni][3] * s);
        if (tx < 9) {
            xwp[(size_t)(16 + tx) * n + node] =
                make_float4(acc1[ni][0] * s, acc1[ni][1] * s, acc1[ni][2] * s, acc1[ni][3] * s);
        }
    }
}

// ================= gather + fused epilogue (plane-major) =================
// block = 256 nodes x 1 plane; random reads confined to one 1.6MB plane (L2-resident)
template <bool RELU>
__global__ __launch_bounds__(256) void gather_kernel(
    const int* __restrict__ rowptr, const int* __restrict__ srcidx,
    const float4* __restrict__ xwp, const float* __restrict__ dis,
    const float* __restrict__ sarr, const float* __restrict__ tarr,
    float4* __restrict__ hp, int n)
{
    const int node = blockIdx.x * 256 + threadIdx.x;
    if (node >= n) return;
    const int q = blockIdx.y;
    const float4* __restrict__ plane = xwp + (size_t)q * n;

    float4 acc = plane[node];               // self-loop term (already *dis[src])
    const int i1 = rowptr[node + 1];
    int i = rowptr[node];
    for (; i + 1 < i1; i += 2) {
        const float4 v0 = plane[srcidx[i]];
        const float4 v1 = plane[srcidx[i + 1]];
        acc.x += v0.x + v1.x;
        acc.y += v0.y + v1.y;
        acc.z += v0.z + v1.z;
        acc.w += v0.w + v1.w;
    }
    if (i < i1) {
        const float4 v0 = plane[srcidx[i]];
        acc.x += v0.x; acc.y += v0.y; acc.z += v0.z; acc.w += v0.w;
    }

    const float dn = dis[node];
    const float4 s  = *reinterpret_cast<const float4*>(&sarr[q * 4]);
    const float4 tt = *reinterpret_cast<const float4*>(&tarr[q * 4]);
    float4 hv;
    hv.x = acc.x * dn * s.x + tt.x;
    hv.y = acc.y * dn * s.y + tt.y;
    hv.z = acc.z * dn * s.z + tt.z;
    hv.w = acc.w * dn * s.w + tt.w;
    if (RELU) {
        hv.x = fmaxf(hv.x, 0.f); hv.y = fmaxf(hv.y, 0.f);
        hv.z = fmaxf(hv.z, 0.f); hv.w = fmaxf(hv.w, 0.f);
    }
    hp[(size_t)q * n + node] = hv;
}

// ================= fused global_add_pool + head + LeakyReLU =================
__global__ __launch_bounds__(64) void pool_head_kernel(
    const float4* __restrict__ hp, const int* __restrict__ batch,
    const float* __restrict__ hW, const float* __restrict__ hb,
    float* __restrict__ out, int n)
{
    const int gi = blockIdx.x;
    int lo = 0, hi = n;
    while (lo < hi) { int mid = (lo + hi) >> 1; if (batch[mid] < gi) lo = mid + 1; else hi = mid; }
    const int start = lo;
    hi = n;
    while (lo < hi) { int mid = (lo + hi) >> 1; if (batch[mid] < gi + 1) lo = mid + 1; else hi = mid; }
    const int end = lo;

    const int q = threadIdx.x;
    float acc = 0.f;
    if (q < NPLANE) {
        const float4 w = *reinterpret_cast<const float4*>(&hW[q * 4]);
        float4 s = make_float4(0.f, 0.f, 0.f, 0.f);
        const float4* __restrict__ plane = hp + (size_t)q * n;
        for (int i = start; i < end; ++i) {
            const float4 v = plane[i];
            s.x += v.x; s.y += v.y; s.z += v.z; s.w += v.w;
        }
        acc = s.x * w.x + s.y * w.y + s.z * w.z + s.w * w.w;
    }
    #pragma unroll
    for (int off = 16; off > 0; off >>= 1) acc += __shfl_down(acc, off);
    if (q == 0) {
        float o = acc + hb[0];
        out[gi] = (o >= 0.f) ? o : 0.1f * o;
    }
}

extern "C" void kernel_launch(void* const* d_in, const int* in_sizes, int n_in,
                              void* d_out, int out_size, void* d_ws, size_t ws_size,
                              hipStream_t stream) {
    const float* x       = (const float*)d_in[0];
    const int*   ei      = (const int*)d_in[1];
    const int*   batch   = (const int*)d_in[2];
    const float* W0      = (const float*)d_in[3];
    const float* Ws      = (const float*)d_in[4];
    const float* biases  = (const float*)d_in[5];
    const float* gamma   = (const float*)d_in[6];
    const float* beta    = (const float*)d_in[7];
    const float* bn_mean = (const float*)d_in[8];
    const float* bn_var  = (const float*)d_in[9];
    const float* headW   = (const float*)d_in[10];
    const float* headb   = (const float*)d_in[11];
    float* out = (float*)d_out;

    const int N = in_sizes[2];
    const int E = in_sizes[1] / 2;
    const int G = out_size;
    const int* row  = ei;
    const int* colp = ei + E;

    char* ws = (char*)d_ws;
    size_t off = 0;
    auto carve = [&](size_t bytes) -> void* {
        void* p = (void*)(ws + off);
        off += (bytes + 255) & ~(size_t)255;
        return p;
    };
    float*  dis    = (float*)carve((size_t)N * 4);
    float4* xwp    = (float4*)carve((size_t)N * NPLANE * 16);
    float4* hbufp  = (float4*)carve((size_t)N * NPLANE * 16);
    int*    degi   = (int*)carve((size_t)N * 4);
    int*    rowptr = (int*)carve((size_t)(N + 1) * 4);
    int*    cursor = (int*)carve((size_t)N * 4);
    int*    srcidx = (int*)carve((size_t)E * 4);
    int*    bsum   = (int*)carve(1024 * 4);
    float*  sarr   = (float*)carve(4 * H100 * 4);
    float*  tarr   = (float*)carve(4 * H100 * 4);

    const int nb_n  = (N + 255) / 256;
    const int nb_e  = (E + 255) / 256;
    const int nb_g  = (N + 63) / 64;
    const dim3 grid_ga((N + 255) / 256, NPLANE);

    // ---- CSR build ----
    hipMemsetAsync(degi, 0, (size_t)N * 4, stream);
    deg_int_kernel<<<nb_e, 256, 0, stream>>>(colp, degi, E);
    scan1_kernel<<<nb_n, 256, 0, stream>>>(degi, rowptr, bsum, N);
    scan2_kernel<<<1, 1024, 0, stream>>>(bsum, nb_n);
    scan3_kernel<<<nb_n, 256, 0, stream>>>(rowptr, bsum, degi, dis, cursor, N);
    fill_csr_kernel<<<nb_e, 256, 0, stream>>>(row, colp, cursor, srcidx, E);
    bnprep_kernel<<<2, 256, 0, stream>>>(biases, gamma, beta, bn_mean, bn_var, sarr, tarr);

    // ---- 4 GCN layers ----
    for (int l = 0; l < 4; ++l) {
        if (l == 0)
            gemm_scale_kernel<33, false><<<nb_g, 256, 0, stream>>>(x, W0, dis, xwp, N);
        else
            gemm_scale_kernel<H100, true><<<nb_g, 256, 0, stream>>>(
                (const float*)hbufp, Ws + (size_t)(l - 1) * H100 * H100, dis, xwp, N);
        if (l < 3)
            gather_kernel<true><<<grid_ga, 256, 0, stream>>>(rowptr, srcidx, xwp, dis,
                                                             sarr + l * H100, tarr + l * H100,
                                                             hbufp, N);
        else
            gather_kernel<false><<<grid_ga, 256, 0, stream>>>(rowptr, srcidx, xwp, dis,
                                                              sarr + l * H100, tarr + l * H100,
                                                              hbufp, N);
    }

    // ---- pool + head ----
    pool_head_kernel<<<G, 64, 0, stream>>>(hbufp, batch, headW, headb, out, N);
}

// Round 4
// 748.393 us; speedup vs baseline: 3.2590x; 3.2590x over previous
//
#include <hip/hip_runtime.h>
#include <hip/hip_bf16.h>

#define H100 100
#define BN_EPS 1e-5f

// ================= CSR build =================
__global__ __launch_bounds__(256) void deg_int_kernel(const int* __restrict__ col,
                                                      int* __restrict__ degi, int E) {
    int t = blockIdx.x * 256 + threadIdx.x;
    if (t < E) atomicAdd(&degi[col[t]], 1);
}

__global__ __launch_bounds__(256) void scan1_kernel(const int* __restrict__ degi,
                                                    int* __restrict__ rowptr,
                                                    int* __restrict__ bsum, int n) {
    __shared__ int lds[256];
    const int t = threadIdx.x;
    const int gid = blockIdx.x * 256 + t;
    int v = (gid < n) ? degi[gid] : 0;
    lds[t] = v;
    __syncthreads();
    for (int off = 1; off < 256; off <<= 1) {
        int u = (t >= off) ? lds[t - off] : 0;
        __syncthreads();
        lds[t] += u;
        __syncthreads();
    }
    if (gid < n) rowptr[gid + 1] = lds[t];
    if (t == 255) bsum[blockIdx.x] = lds[t];
}

__global__ __launch_bounds__(1024) void scan2_kernel(int* __restrict__ bsum, int nb) {
    __shared__ int lds[1024];
    const int t = threadIdx.x;
    int v = (t < nb) ? bsum[t] : 0;
    lds[t] = v;
    __syncthreads();
    for (int off = 1; off < 1024; off <<= 1) {
        int u = (t >= off) ? lds[t - off] : 0;
        __syncthreads();
        lds[t] += u;
        __syncthreads();
    }
    if (t < nb) bsum[t] = lds[t] - v;   // exclusive
}

__global__ __launch_bounds__(256) void scan3_kernel(int* __restrict__ rowptr,
                                                    const int* __restrict__ bsum,
                                                    const int* __restrict__ degi,
                                                    float* __restrict__ dis,
                                                    int* __restrict__ cursor, int n) {
    const int gid = blockIdx.x * 256 + threadIdx.x;
    if (gid >= n) return;
    const int d = degi[gid];
    const int rp1 = rowptr[gid + 1] + bsum[blockIdx.x];
    rowptr[gid + 1] = rp1;
    cursor[gid] = rp1 - d;
    if (gid == 0) rowptr[0] = 0;
    dis[gid] = rsqrtf((float)(d + 1));
}

__global__ __launch_bounds__(256) void fill_csr_kernel(const int* __restrict__ row,
                                                       const int* __restrict__ col,
                                                       int* __restrict__ cursor,
                                                       int* __restrict__ srcidx, int E) {
    int e = blockIdx.x * 256 + threadIdx.x;
    if (e >= E) return;
    int slot = atomicAdd(&cursor[col[e]], 1);
    srcidx[slot] = row[e];
}

// ================= parameter prep =================
__global__ __launch_bounds__(256) void bnprep_kernel(const float* __restrict__ b,
                                                     const float* __restrict__ gamma,
                                                     const float* __restrict__ beta,
                                                     const float* __restrict__ mean,
                                                     const float* __restrict__ var,
                                                     float* __restrict__ sarr,
                                                     float* __restrict__ tarr) {
    int idx = blockIdx.x * 256 + threadIdx.x;
    if (idx >= 4 * H100) return;
    float s = gamma[idx] * rsqrtf(var[idx] + BN_EPS);
    sarr[idx] = s;
    tarr[idx] = (b[idx] - mean[idx]) * s + beta[idx];
}

// wp = W3 @ (s3 .* headW), c3 = t3 . headW    (one block, 128 threads)
__global__ __launch_bounds__(128) void headprep_kernel(const float* __restrict__ W3,
                                                       const float* __restrict__ headW,
                                                       const float* __restrict__ sarr3,
                                                       const float* __restrict__ tarr3,
                                                       float* __restrict__ wp,
                                                       float* __restrict__ c3) {
    __shared__ float ws_[H100];
    const int t = threadIdx.x;
    if (t < H100) ws_[t] = sarr3[t] * headW[t];
    __syncthreads();
    if (t < H100) {
        float acc = 0.f;
        for (int c = 0; c < H100; ++c) acc += W3[t * H100 + c] * ws_[c];
        wp[t] = acc;
    }
    if (t == 0) {
        float acc = 0.f;
        for (int c = 0; c < H100; ++c) acc += tarr3[c] * headW[c];
        *c3 = acc;
    }
}

// Wpad[36][100] = W0 zero-padded in K
__global__ __launch_bounds__(256) void wpad_kernel(const float* __restrict__ W0,
                                                   float* __restrict__ Wpad) {
    int idx = blockIdx.x * 256 + threadIdx.x;
    if (idx >= 36 * H100) return;
    Wpad[idx] = (idx < 33 * H100) ? W0[idx] : 0.f;
}

// xt[i][0..35] = dis[i] * x[i][0..32], padded with zeros (float4[N*9])
__global__ __launch_bounds__(256) void xprep_kernel(const float* __restrict__ x,
                                                    const float* __restrict__ dis,
                                                    float4* __restrict__ xt, int n) {
    int t = blockIdx.x * 256 + threadIdx.x;
    int node = t / 9;
    if (node >= n) return;
    int q = t - node * 9;
    const float d = dis[node];
    float v[4];
    #pragma unroll
    for (int j = 0; j < 4; ++j) {
        int c = q * 4 + j;
        v[j] = (c < 33) ? x[node * 33 + c] * d : 0.f;
    }
    xt[node * 9 + q] = make_float4(v[0], v[1], v[2], v[3]);
}

// ================= gather 33-dim (padded 36): agg0 = A_norm x =================
__global__ __launch_bounds__(256) void gather33_kernel(
    const int* __restrict__ rowptr, const int* __restrict__ srcidx,
    const float4* __restrict__ xt, const float* __restrict__ dis,
    float4* __restrict__ agg0, int n)
{
    const int t = blockIdx.x * 256 + threadIdx.x;
    const int node = t / 9;
    if (node >= n) return;
    const int q = t - node * 9;

    float4 acc = xt[node * 9 + q];          // self-loop (already *dis[node])
    const int i1 = rowptr[node + 1];
    int i = rowptr[node];
    for (; i + 1 < i1; i += 2) {
        const float4 v0 = xt[srcidx[i] * 9 + q];
        const float4 v1 = xt[srcidx[i + 1] * 9 + q];
        acc.x += v0.x + v1.x; acc.y += v0.y + v1.y;
        acc.z += v0.z + v1.z; acc.w += v0.w + v1.w;
    }
    if (i < i1) {
        const float4 v0 = xt[srcidx[i] * 9 + q];
        acc.x += v0.x; acc.y += v0.y; acc.z += v0.z; acc.w += v0.w;
    }
    const float d = dis[node];
    agg0[node * 9 + q] = make_float4(acc.x * d, acc.y * d, acc.z * d, acc.w * d);
}

// ================= GEMM (node-major in/out) =================
// EPI==0: out = (hin@W) * dis[i]         (message prep)
// EPI==1: out = relu(bn(hin@W))          (sarr/tarr layer-folded, bias inside tarr)
template <int CIN, int EPI>
__global__ __launch_bounds__(256) void gemm_kernel(
    const float* __restrict__ hin, const float* __restrict__ W,
    const float* __restrict__ dis, const float* __restrict__ sarr,
    const float* __restrict__ tarr, float* __restrict__ hout, int n)
{
    constexpr int KH = (CIN + 1) / 2;
    __shared__ float Wl[KH * H100 + 32];
    __shared__ float hsT[CIN * 68];
    const int tid = threadIdx.x;
    const int node0 = blockIdx.x * 64;

    for (int idx = tid; idx < 64 * CIN; idx += 256) {
        int r = idx / CIN;
        int k = idx - r * CIN;
        int node = node0 + r;
        hsT[k * 68 + r] = (node < n) ? hin[node * CIN + k] : 0.0f;
    }

    const int tx = tid & 15;
    const int ty = tid >> 4;
    float acc0[4][4] = {{0.f}};
    float acc1[4][4] = {{0.f}};

    for (int p = 0; p < 2; ++p) {
        const int k0 = p * KH;
        const int kn = (CIN - k0 < KH) ? (CIN - k0) : KH;
        __syncthreads();
        for (int idx = tid; idx < kn * H100; idx += 256)
            Wl[idx] = W[k0 * H100 + idx];
        __syncthreads();
        for (int kk = 0; kk < kn; ++kk) {
            const float4 a  = *reinterpret_cast<const float4*>(&hsT[(k0 + kk) * 68 + ty * 4]);
            const float4 w0 = *reinterpret_cast<const float4*>(&Wl[kk * H100 + tx * 4]);
            const float4 w1 = *reinterpret_cast<const float4*>(&Wl[kk * H100 + 64 + tx * 4]);
            const float av[4]  = {a.x, a.y, a.z, a.w};
            const float w0v[4] = {w0.x, w0.y, w0.z, w0.w};
            const float w1v[4] = {w1.x, w1.y, w1.z, w1.w};
            #pragma unroll
            for (int ni = 0; ni < 4; ++ni)
                #pragma unroll
                for (int ci = 0; ci < 4; ++ci) {
                    acc0[ni][ci] += av[ni] * w0v[ci];
                    acc1[ni][ci] += av[ni] * w1v[ci];
                }
        }
    }

    float4 s0, s1, t0, t1;
    if (EPI == 1) {
        s0 = *reinterpret_cast<const float4*>(&sarr[tx * 4]);
        t0 = *reinterpret_cast<const float4*>(&tarr[tx * 4]);
        if (tx < 9) {
            s1 = *reinterpret_cast<const float4*>(&sarr[64 + tx * 4]);
            t1 = *reinterpret_cast<const float4*>(&tarr[64 + tx * 4]);
        }
    }

    #pragma unroll
    for (int ni = 0; ni < 4; ++ni) {
        const int node = node0 + ty * 4 + ni;
        if (node >= n) continue;
        float4 o0, o1;
        if (EPI == 0) {
            const float d = dis[node];
            o0 = make_float4(acc0[ni][0] * d, acc0[ni][1] * d, acc0[ni][2] * d, acc0[ni][3] * d);
            o1 = make_float4(acc1[ni][0] * d, acc1[ni][1] * d, acc1[ni][2] * d, acc1[ni][3] * d);
        } else {
            o0.x = fmaxf(acc0[ni][0] * s0.x + t0.x, 0.f);
            o0.y = fmaxf(acc0[ni][1] * s0.y + t0.y, 0.f);
            o0.z = fmaxf(acc0[ni][2] * s0.z + t0.z, 0.f);
            o0.w = fmaxf(acc0[ni][3] * s0.w + t0.w, 0.f);
            if (tx < 9) {
                o1.x = fmaxf(acc1[ni][0] * s1.x + t1.x, 0.f);
                o1.y = fmaxf(acc1[ni][1] * s1.y + t1.y, 0.f);
                o1.z = fmaxf(acc1[ni][2] * s1.z + t1.z, 0.f);
                o1.w = fmaxf(acc1[ni][3] * s1.w + t1.w, 0.f);
            }
        }
        *reinterpret_cast<float4*>(&hout[node * H100 + tx * 4]) = o0;
        if (tx < 9)
            *reinterpret_cast<float4*>(&hout[node * H100 + 64 + tx * 4]) = o1;
    }
}

// ================= gather 100-dim (node-major, 25 thr/node, 10 nodes/block) ====
// MODE 0: hout[node] = relu(bn(dis*(sum+self)))                 (layers 1,2 -> h)
// MODE 1: y[node] = dis[node] * (relu(bn(...)) . wp)            (layer-2 out fused with rank-1 head)
template <int MODE>
__global__ __launch_bounds__(256) void gather100_kernel(
    const int* __restrict__ rowptr, const int* __restrict__ srcidx,
    const float4* __restrict__ z4, const float* __restrict__ dis,
    const float* __restrict__ sarr, const float* __restrict__ tarr,
    const float* __restrict__ wp, float4* __restrict__ hout,
    float* __restrict__ y, int n)
{
    const int tid = threadIdx.x;
    const int node = blockIdx.x * 10 + tid / 25;
    const int q = tid % 25;
    const bool valid = (tid < 250) && (node < n);

    float4 acc = make_float4(0.f, 0.f, 0.f, 0.f);
    float dn = 0.f;
    if (valid) {
        acc = z4[node * 25 + q];            // self-loop (already *dis)
        dn = dis[node];
        const int i1 = rowptr[node + 1];
        int i = rowptr[node];
        for (; i + 1 < i1; i += 2) {
            const float4 v0 = z4[srcidx[i] * 25 + q];
            const float4 v1 = z4[srcidx[i + 1] * 25 + q];
            acc.x += v0.x + v1.x; acc.y += v0.y + v1.y;
            acc.z += v0.z + v1.z; acc.w += v0.w + v1.w;
        }
        if (i < i1) {
            const float4 v0 = z4[srcidx[i] * 25 + q];
            acc.x += v0.x; acc.y += v0.y; acc.z += v0.z; acc.w += v0.w;
        }
    }

    const float4 s  = *reinterpret_cast<const float4*>(&sarr[q * 4]);
    const float4 tt = *reinterpret_cast<const float4*>(&tarr[q * 4]);
    float4 hv;
    hv.x = fmaxf(acc.x * dn * s.x + tt.x, 0.f);
    hv.y = fmaxf(acc.y * dn * s.y + tt.y, 0.f);
    hv.z = fmaxf(acc.z * dn * s.z + tt.z, 0.f);
    hv.w = fmaxf(acc.w * dn * s.w + tt.w, 0.f);

    if (MODE == 0) {
        if (valid) hout[node * 25 + q] = hv;
    } else {
        const float4 w = *reinterpret_cast<const float4*>(&wp[q * 4]);
        float partial = hv.x * w.x + hv.y * w.y + hv.z * w.z + hv.w * w.w;
        __shared__ float red[256];
        red[tid] = valid ? partial : 0.f;
        __syncthreads();
        if (q == 0 && valid) {
            float sum = 0.f;
            #pragma unroll
            for (int j = 0; j < 25; ++j) sum += red[tid + j];
            y[node] = sum * dn;
        }
    }
}

// ================= scalar gather (layer 3 collapsed) + pool via atomics =======
__global__ __launch_bounds__(256) void gather_scalar_kernel(
    const int* __restrict__ rowptr, const int* __restrict__ srcidx,
    const float* __restrict__ y, const float* __restrict__ dis,
    const float* __restrict__ c3, const int* __restrict__ batch,
    float* __restrict__ gacc, int n)
{
    const int node = blockIdx.x * 256 + threadIdx.x;
    if (node >= n) return;
    float acc = y[node];                    // self-loop
    const int i1 = rowptr[node + 1];
    int i = rowptr[node];
    for (; i + 3 < i1; i += 4) {
        const int s0 = srcidx[i], s1 = srcidx[i + 1], s2 = srcidx[i + 2], s3 = srcidx[i + 3];
        acc += y[s0] + y[s1] + y[s2] + y[s3];
    }
    for (; i < i1; ++i) acc += y[srcidx[i]];
    unsafeAtomicAdd(&gacc[batch[node]], dis[node] * acc + c3[0]);
}

__global__ __launch_bounds__(256) void finish_kernel(const float* __restrict__ gacc,
                                                     const float* __restrict__ hb,
                                                     float* __restrict__ out, int G) {
    int g = blockIdx.x * 256 + threadIdx.x;
    if (g >= G) return;
    float o = gacc[g] + hb[0];
    out[g] = (o >= 0.f) ? o : 0.1f * o;
}

extern "C" void kernel_launch(void* const* d_in, const int* in_sizes, int n_in,
                              void* d_out, int out_size, void* d_ws, size_t ws_size,
                              hipStream_t stream) {
    const float* x       = (const float*)d_in[0];
    const int*   ei      = (const int*)d_in[1];
    const int*   batch   = (const int*)d_in[2];
    const float* W0      = (const float*)d_in[3];
    const float* Ws      = (const float*)d_in[4];
    const float* biases  = (const float*)d_in[5];
    const float* gamma   = (const float*)d_in[6];
    const float* beta    = (const float*)d_in[7];
    const float* bn_mean = (const float*)d_in[8];
    const float* bn_var  = (const float*)d_in[9];
    const float* headW   = (const float*)d_in[10];
    const float* headb   = (const float*)d_in[11];
    float* out = (float*)d_out;

    const int N = in_sizes[2];
    const int E = in_sizes[1] / 2;
    const int G = out_size;
    const int* row  = ei;
    const int* colp = ei + E;

    char* ws = (char*)d_ws;
    size_t off = 0;
    auto carve = [&](size_t bytes) -> void* {
        void* p = (void*)(ws + off);
        off += (bytes + 255) & ~(size_t)255;
        return p;
    };
    float*  dis    = (float*)carve((size_t)N * 4);
    float4* xt     = (float4*)carve((size_t)N * 9 * 16);
    float4* agg0   = (float4*)carve((size_t)N * 9 * 16);
    float*  bufA   = (float*)carve((size_t)N * H100 * 4);
    float*  bufB   = (float*)carve((size_t)N * H100 * 4);
    float*  y      = (float*)carve((size_t)N * 4);
    int*    degi   = (int*)carve((size_t)N * 4);
    int*    rowptr = (int*)carve((size_t)(N + 1) * 4);
    int*    cursor = (int*)carve((size_t)N * 4);
    int*    srcidx = (int*)carve((size_t)E * 4);
    int*    bsum   = (int*)carve(1024 * 4);
    float*  sarr   = (float*)carve(4 * H100 * 4);
    float*  tarr   = (float*)carve(4 * H100 * 4);
    float*  wp     = (float*)carve(H100 * 4);
    float*  c3     = (float*)carve(256);
    float*  Wpad   = (float*)carve(36 * H100 * 4);
    float*  gacc   = (float*)carve((size_t)G * 4);

    const int nb_n  = (N + 255) / 256;
    const int nb_e  = (E + 255) / 256;
    const int nb_g  = (N + 63) / 64;
    const int nb_9  = (N * 9 + 255) / 256;
    const int nb_ga = (N + 9) / 10;

    // ---- CSR + params ----
    hipMemsetAsync(degi, 0, (size_t)N * 4, stream);
    deg_int_kernel<<<nb_e, 256, 0, stream>>>(colp, degi, E);
    scan1_kernel<<<nb_n, 256, 0, stream>>>(degi, rowptr, bsum, N);
    scan2_kernel<<<1, 1024, 0, stream>>>(bsum, nb_n);
    scan3_kernel<<<nb_n, 256, 0, stream>>>(rowptr, bsum, degi, dis, cursor, N);
    fill_csr_kernel<<<nb_e, 256, 0, stream>>>(row, colp, cursor, srcidx, E);
    bnprep_kernel<<<2, 256, 0, stream>>>(biases, gamma, beta, bn_mean, bn_var, sarr, tarr);
    headprep_kernel<<<1, 128, 0, stream>>>(Ws + 2 * H100 * H100, headW,
                                           sarr + 3 * H100, tarr + 3 * H100, wp, c3);
    wpad_kernel<<<(36 * H100 + 255) / 256, 256, 0, stream>>>(W0, Wpad);
    xprep_kernel<<<nb_9, 256, 0, stream>>>(x, dis, xt, N);

    // ---- layer 0: aggregate x (33-dim), then GEMM 36->100 with BN+ReLU ----
    gather33_kernel<<<nb_9, 256, 0, stream>>>(rowptr, srcidx, xt, dis, agg0, N);
    gemm_kernel<36, 1><<<nb_g, 256, 0, stream>>>((const float*)agg0, Wpad, dis,
                                                 sarr, tarr, bufA, N);   // h1

    // ---- layer 1 ----
    gemm_kernel<H100, 0><<<nb_g, 256, 0, stream>>>(bufA, Ws, dis, nullptr, nullptr, bufB, N); // z1
    gather100_kernel<0><<<nb_ga, 256, 0, stream>>>(rowptr, srcidx, (const float4*)bufB, dis,
                                                   sarr + H100, tarr + H100, nullptr,
                                                   (float4*)bufA, nullptr, N);               // h2

    // ---- layer 2 (+ fused rank-1 head projection) ----
    gemm_kernel<H100, 0><<<nb_g, 256, 0, stream>>>(bufA, Ws + H100 * H100, dis,
                                                   nullptr, nullptr, bufB, N);               // z2
    gather100_kernel<1><<<nb_ga, 256, 0, stream>>>(rowptr, srcidx, (const float4*)bufB, dis,
                                                   sarr + 2 * H100, tarr + 2 * H100, wp,
                                                   nullptr, y, N);                           // y

    // ---- layer 3 collapsed to scalar gather + pool ----
    hipMemsetAsync(gacc, 0, (size_t)G * 4, stream);
    gather_scalar_kernel<<<nb_n, 256, 0, stream>>>(rowptr, srcidx, y, dis, c3, batch, gacc, N);
    finish_kernel<<<(G + 255) / 256, 256, 0, stream>>>(gacc, headb, out, G);
}

// Round 5
// 693.554 us; speedup vs baseline: 3.5166x; 1.0791x over previous
//
#include <hip/hip_runtime.h>
#include <hip/hip_bf16.h>

#define H100 100
#define BN_EPS 1e-5f
#define NBKT 8          // one bucket per XCD
#define NSLICE 200      // edge slices per bucket

// ================= bucketed degree count (XCD-local atomics) =================
// block i: bucket (i&7), edge chunk (i>>3). All atomics for a bucket stay on one XCD's L2.
__global__ __launch_bounds__(256) void deg_bucket_kernel(const int* __restrict__ col,
                                                         int* __restrict__ degi,
                                                         int E, int npb, int chunk) {
    const int bkt = blockIdx.x & (NBKT - 1);
    const int slice = blockIdx.x >> 3;
    const int lo = bkt * npb, hi = lo + npb;
    const int e0 = slice * chunk;
    const int e1 = (e0 + chunk < E) ? e0 + chunk : E;
    for (int e = e0 + threadIdx.x; e < e1; e += 256) {
        int c = col[e];
        if (c >= lo && c < hi) atomicAdd(&degi[c], 1);
    }
}

// ================= scans =================
__global__ __launch_bounds__(256) void scan1_kernel(const int* __restrict__ degi,
                                                    int* __restrict__ rowptr,
                                                    int* __restrict__ bsum, int n) {
    __shared__ int lds[256];
    const int t = threadIdx.x;
    const int gid = blockIdx.x * 256 + t;
    int v = (gid < n) ? degi[gid] : 0;
    lds[t] = v;
    __syncthreads();
    for (int off = 1; off < 256; off <<= 1) {
        int u = (t >= off) ? lds[t - off] : 0;
        __syncthreads();
        lds[t] += u;
        __syncthreads();
    }
    if (gid < n) rowptr[gid + 1] = lds[t];
    if (t == 255) bsum[blockIdx.x] = lds[t];
}

__global__ __launch_bounds__(1024) void scan2_kernel(int* __restrict__ bsum, int nb) {
    __shared__ int lds[1024];
    const int t = threadIdx.x;
    int v = (t < nb) ? bsum[t] : 0;
    lds[t] = v;
    __syncthreads();
    for (int off = 1; off < 1024; off <<= 1) {
        int u = (t >= off) ? lds[t - off] : 0;
        __syncthreads();
        lds[t] += u;
        __syncthreads();
    }
    if (t < nb) bsum[t] = lds[t] - v;   // exclusive
}

__global__ __launch_bounds__(256) void scan3_kernel(int* __restrict__ rowptr,
                                                    const int* __restrict__ bsum,
                                                    const int* __restrict__ degi,
                                                    float* __restrict__ dis,
                                                    int* __restrict__ cursor, int n) {
    const int gid = blockIdx.x * 256 + threadIdx.x;
    if (gid >= n) return;
    const int d = degi[gid];
    const int rp1 = rowptr[gid + 1] + bsum[blockIdx.x];
    rowptr[gid + 1] = rp1;
    cursor[gid] = rp1 - d;
    if (gid == 0) rowptr[0] = 0;
    dis[gid] = rsqrtf((float)(d + 1));
}

// ================= bucketed CSR fill (XCD-local cursor atomics + srcidx writes) ==
__global__ __launch_bounds__(256) void fill_bucket_kernel(const int* __restrict__ row,
                                                          const int* __restrict__ col,
                                                          int* __restrict__ cursor,
                                                          int* __restrict__ srcidx,
                                                          int E, int npb, int chunk) {
    const int bkt = blockIdx.x & (NBKT - 1);
    const int slice = blockIdx.x >> 3;
    const int lo = bkt * npb, hi = lo + npb;
    const int e0 = slice * chunk;
    const int e1 = (e0 + chunk < E) ? e0 + chunk : E;
    for (int e = e0 + threadIdx.x; e < e1; e += 256) {
        int c = col[e];
        if (c >= lo && c < hi) {
            int slot = atomicAdd(&cursor[c], 1);
            srcidx[slot] = row[e];
        }
    }
}

// ================= fused parameter prep: BN fold + W0 pad =================
__global__ __launch_bounds__(256) void prep_kernel(const float* __restrict__ b,
                                                   const float* __restrict__ gamma,
                                                   const float* __restrict__ beta,
                                                   const float* __restrict__ mean,
                                                   const float* __restrict__ var,
                                                   const float* __restrict__ W0,
                                                   float* __restrict__ sarr,
                                                   float* __restrict__ tarr,
                                                   float* __restrict__ Wpad) {
    int idx = blockIdx.x * 256 + threadIdx.x;
    if (idx < 4 * H100) {
        float s = gamma[idx] * rsqrtf(var[idx] + BN_EPS);
        sarr[idx] = s;
        tarr[idx] = (b[idx] - mean[idx]) * s + beta[idx];
    }
    int widx = idx - 4 * H100;
    if (widx >= 0 && widx < 36 * H100)
        Wpad[widx] = (widx < 33 * H100) ? W0[widx] : 0.f;
}

// wp = W3 @ (s3 .* headW), c3 = t3 . headW
__global__ __launch_bounds__(128) void headprep_kernel(const float* __restrict__ W3,
                                                       const float* __restrict__ headW,
                                                       const float* __restrict__ sarr3,
                                                       const float* __restrict__ tarr3,
                                                       float* __restrict__ wp,
                                                       float* __restrict__ c3) {
    __shared__ float ws_[H100];
    const int t = threadIdx.x;
    if (t < H100) ws_[t] = sarr3[t] * headW[t];
    __syncthreads();
    if (t < H100) {
        float acc = 0.f;
        for (int c = 0; c < H100; ++c) acc += W3[t * H100 + c] * ws_[c];
        wp[t] = acc;
    }
    if (t == 0) {
        float acc = 0.f;
        for (int c = 0; c < H100; ++c) acc += tarr3[c] * headW[c];
        *c3 = acc;
    }
}

// xt[i][0..35] = dis[i] * x[i][0..32], zero-padded (float4[N*9])
__global__ __launch_bounds__(256) void xprep_kernel(const float* __restrict__ x,
                                                    const float* __restrict__ dis,
                                                    float4* __restrict__ xt, int n) {
    int t = blockIdx.x * 256 + threadIdx.x;
    int node = t / 9;
    if (node >= n) return;
    int q = t - node * 9;
    const float d = dis[node];
    float v[4];
    #pragma unroll
    for (int j = 0; j < 4; ++j) {
        int c = q * 4 + j;
        v[j] = (c < 33) ? x[node * 33 + c] * d : 0.f;
    }
    xt[node * 9 + q] = make_float4(v[0], v[1], v[2], v[3]);
}

// ================= gather 33-dim: agg0 = A_norm x (9 thr-groups/node) ==========
__global__ __launch_bounds__(256) void gather33_kernel(
    const int* __restrict__ rowptr, const int* __restrict__ srcidx,
    const float4* __restrict__ xt, const float* __restrict__ dis,
    float4* __restrict__ agg0, int n)
{
    const int t = blockIdx.x * 256 + threadIdx.x;
    const int node = t / 9;
    if (node >= n) return;
    const int q = t - node * 9;

    float4 a0 = xt[node * 9 + q];           // self-loop
    float4 a1 = make_float4(0.f, 0.f, 0.f, 0.f);
    const int i1 = rowptr[node + 1];
    int i = rowptr[node];
    for (; i + 3 < i1; i += 4) {
        const int s0 = srcidx[i], s1 = srcidx[i + 1], s2 = srcidx[i + 2], s3 = srcidx[i + 3];
        const float4 v0 = xt[s0 * 9 + q];
        const float4 v1 = xt[s1 * 9 + q];
        const float4 v2 = xt[s2 * 9 + q];
        const float4 v3 = xt[s3 * 9 + q];
        a0.x += v0.x + v1.x; a0.y += v0.y + v1.y; a0.z += v0.z + v1.z; a0.w += v0.w + v1.w;
        a1.x += v2.x + v3.x; a1.y += v2.y + v3.y; a1.z += v2.z + v3.z; a1.w += v2.w + v3.w;
    }
    for (; i < i1; ++i) {
        const float4 v0 = xt[srcidx[i] * 9 + q];
        a0.x += v0.x; a0.y += v0.y; a0.z += v0.z; a0.w += v0.w;
    }
    const float d = dis[node];
    agg0[node * 9 + q] = make_float4((a0.x + a1.x) * d, (a0.y + a1.y) * d,
                                     (a0.z + a1.z) * d, (a0.w + a1.w) * d);
}

// ================= GEMM (node-major in/out) =================
template <int CIN, int EPI>
__global__ __launch_bounds__(256) void gemm_kernel(
    const float* __restrict__ hin, const float* __restrict__ W,
    const float* __restrict__ dis, const float* __restrict__ sarr,
    const float* __restrict__ tarr, float* __restrict__ hout, int n)
{
    constexpr int KH = (CIN + 1) / 2;
    __shared__ float Wl[KH * H100 + 32];
    __shared__ float hsT[CIN * 68];
    const int tid = threadIdx.x;
    const int node0 = blockIdx.x * 64;

    for (int idx = tid; idx < 64 * CIN; idx += 256) {
        int r = idx / CIN;
        int k = idx - r * CIN;
        int node = node0 + r;
        hsT[k * 68 + r] = (node < n) ? hin[node * CIN + k] : 0.0f;
    }

    const int tx = tid & 15;
    const int ty = tid >> 4;
    float acc0[4][4] = {{0.f}};
    float acc1[4][4] = {{0.f}};

    for (int p = 0; p < 2; ++p) {
        const int k0 = p * KH;
        const int kn = (CIN - k0 < KH) ? (CIN - k0) : KH;
        __syncthreads();
        for (int idx = tid; idx < kn * H100; idx += 256)
            Wl[idx] = W[k0 * H100 + idx];
        __syncthreads();
        for (int kk = 0; kk < kn; ++kk) {
            const float4 a  = *reinterpret_cast<const float4*>(&hsT[(k0 + kk) * 68 + ty * 4]);
            const float4 w0 = *reinterpret_cast<const float4*>(&Wl[kk * H100 + tx * 4]);
            const float4 w1 = *reinterpret_cast<const float4*>(&Wl[kk * H100 + 64 + tx * 4]);
            const float av[4]  = {a.x, a.y, a.z, a.w};
            const float w0v[4] = {w0.x, w0.y, w0.z, w0.w};
            const float w1v[4] = {w1.x, w1.y, w1.z, w1.w};
            #pragma unroll
            for (int ni = 0; ni < 4; ++ni)
                #pragma unroll
                for (int ci = 0; ci < 4; ++ci) {
                    acc0[ni][ci] += av[ni] * w0v[ci];
                    acc1[ni][ci] += av[ni] * w1v[ci];
                }
        }
    }

    float4 s0, s1, t0, t1;
    if (EPI == 1) {
        s0 = *reinterpret_cast<const float4*>(&sarr[tx * 4]);
        t0 = *reinterpret_cast<const float4*>(&tarr[tx * 4]);
        if (tx < 9) {
            s1 = *reinterpret_cast<const float4*>(&sarr[64 + tx * 4]);
            t1 = *reinterpret_cast<const float4*>(&tarr[64 + tx * 4]);
        }
    }

    #pragma unroll
    for (int ni = 0; ni < 4; ++ni) {
        const int node = node0 + ty * 4 + ni;
        if (node >= n) continue;
        float4 o0, o1;
        if (EPI == 0) {
            const float d = dis[node];
            o0 = make_float4(acc0[ni][0] * d, acc0[ni][1] * d, acc0[ni][2] * d, acc0[ni][3] * d);
            o1 = make_float4(acc1[ni][0] * d, acc1[ni][1] * d, acc1[ni][2] * d, acc1[ni][3] * d);
        } else {
            o0.x = fmaxf(acc0[ni][0] * s0.x + t0.x, 0.f);
            o0.y = fmaxf(acc0[ni][1] * s0.y + t0.y, 0.f);
            o0.z = fmaxf(acc0[ni][2] * s0.z + t0.z, 0.f);
            o0.w = fmaxf(acc0[ni][3] * s0.w + t0.w, 0.f);
            if (tx < 9) {
                o1.x = fmaxf(acc1[ni][0] * s1.x + t1.x, 0.f);
                o1.y = fmaxf(acc1[ni][1] * s1.y + t1.y, 0.f);
                o1.z = fmaxf(acc1[ni][2] * s1.z + t1.z, 0.f);
                o1.w = fmaxf(acc1[ni][3] * s1.w + t1.w, 0.f);
            }
        }
        *reinterpret_cast<float4*>(&hout[node * H100 + tx * 4]) = o0;
        if (tx < 9)
            *reinterpret_cast<float4*>(&hout[node * H100 + 64 + tx * 4]) = o1;
    }
}

// ================= gather 100-dim (25 thr/node, 10 nodes/block) ================
// MODE 0: hout = relu(bn(dis*(sum+self)))
// MODE 1: y[node] = dis * (relu(bn(...)) . wp)   (rank-1 head fused)
template <int MODE>
__global__ __launch_bounds__(256) void gather100_kernel(
    const int* __restrict__ rowptr, const int* __restrict__ srcidx,
    const float4* __restrict__ z4, const float* __restrict__ dis,
    const float* __restrict__ sarr, const float* __restrict__ tarr,
    const float* __restrict__ wp, float4* __restrict__ hout,
    float* __restrict__ y, int n)
{
    const int tid = threadIdx.x;
    const int node = blockIdx.x * 10 + tid / 25;
    const int q = tid % 25;
    const bool valid = (tid < 250) && (node < n);

    float4 a0 = make_float4(0.f, 0.f, 0.f, 0.f);
    float4 a1 = make_float4(0.f, 0.f, 0.f, 0.f);
    float dn = 0.f;
    if (valid) {
        a0 = z4[node * 25 + q];             // self-loop
        dn = dis[node];
        const int i1 = rowptr[node + 1];
        int i = rowptr[node];
        for (; i + 3 < i1; i += 4) {
            const int s0 = srcidx[i], s1 = srcidx[i + 1], s2 = srcidx[i + 2], s3 = srcidx[i + 3];
            const float4 v0 = z4[s0 * 25 + q];
            const float4 v1 = z4[s1 * 25 + q];
            const float4 v2 = z4[s2 * 25 + q];
            const float4 v3 = z4[s3 * 25 + q];
            a0.x += v0.x + v1.x; a0.y += v0.y + v1.y; a0.z += v0.z + v1.z; a0.w += v0.w + v1.w;
            a1.x += v2.x + v3.x; a1.y += v2.y + v3.y; a1.z += v2.z + v3.z; a1.w += v2.w + v3.w;
        }
        for (; i < i1; ++i) {
            const float4 v0 = z4[srcidx[i] * 25 + q];
            a0.x += v0.x; a0.y += v0.y; a0.z += v0.z; a0.w += v0.w;
        }
    }
    float4 acc = make_float4(a0.x + a1.x, a0.y + a1.y, a0.z + a1.z, a0.w + a1.w);

    const float4 s  = *reinterpret_cast<const float4*>(&sarr[q * 4]);
    const float4 tt = *reinterpret_cast<const float4*>(&tarr[q * 4]);
    float4 hv;
    hv.x = fmaxf(acc.x * dn * s.x + tt.x, 0.f);
    hv.y = fmaxf(acc.y * dn * s.y + tt.y, 0.f);
    hv.z = fmaxf(acc.z * dn * s.z + tt.z, 0.f);
    hv.w = fmaxf(acc.w * dn * s.w + tt.w, 0.f);

    if (MODE == 0) {
        if (valid) hout[node * 25 + q] = hv;
    } else {
        const float4 w = *reinterpret_cast<const float4*>(&wp[q * 4]);
        float partial = hv.x * w.x + hv.y * w.y + hv.z * w.z + hv.w * w.w;
        __shared__ float red[256];
        red[tid] = valid ? partial : 0.f;
        __syncthreads();
        if (q == 0 && valid) {
            float sum = 0.f;
            #pragma unroll
            for (int j = 0; j < 25; ++j) sum += red[tid + j];
            y[node] = sum * dn;
        }
    }
}

// ================= scalar gather (layer 3 collapsed) + pool =================
__global__ __launch_bounds__(256) void gather_scalar_kernel(
    const int* __restrict__ rowptr, const int* __restrict__ srcidx,
    const float* __restrict__ y, const float* __restrict__ dis,
    const float* __restrict__ c3, const int* __restrict__ batch,
    float* __restrict__ gacc, int n)
{
    const int node = blockIdx.x * 256 + threadIdx.x;
    if (node >= n) return;
    float acc = y[node];
    const int i1 = rowptr[node + 1];
    int i = rowptr[node];
    for (; i + 3 < i1; i += 4) {
        const int s0 = srcidx[i], s1 = srcidx[i + 1], s2 = srcidx[i + 2], s3 = srcidx[i + 3];
        acc += y[s0] + y[s1] + y[s2] + y[s3];
    }
    for (; i < i1; ++i) acc += y[srcidx[i]];
    unsafeAtomicAdd(&gacc[batch[node]], dis[node] * acc + c3[0]);
}

__global__ __launch_bounds__(256) void finish_kernel(const float* __restrict__ gacc,
                                                     const float* __restrict__ hb,
                                                     float* __restrict__ out, int G) {
    int g = blockIdx.x * 256 + threadIdx.x;
    if (g >= G) return;
    float o = gacc[g] + hb[0];
    out[g] = (o >= 0.f) ? o : 0.1f * o;
}

extern "C" void kernel_launch(void* const* d_in, const int* in_sizes, int n_in,
                              void* d_out, int out_size, void* d_ws, size_t ws_size,
                              hipStream_t stream) {
    const float* x       = (const float*)d_in[0];
    const int*   ei      = (const int*)d_in[1];
    const int*   batch   = (const int*)d_in[2];
    const float* W0      = (const float*)d_in[3];
    const float* Ws      = (const float*)d_in[4];
    const float* biases  = (const float*)d_in[5];
    const float* gamma   = (const float*)d_in[6];
    const float* beta    = (const float*)d_in[7];
    const float* bn_mean = (const float*)d_in[8];
    const float* bn_var  = (const float*)d_in[9];
    const float* headW   = (const float*)d_in[10];
    const float* headb   = (const float*)d_in[11];
    float* out = (float*)d_out;

    const int N = in_sizes[2];
    const int E = in_sizes[1] / 2;
    const int G = out_size;
    const int* row  = ei;
    const int* colp = ei + E;

    char* ws = (char*)d_ws;
    size_t off = 0;
    auto carve = [&](size_t bytes) -> void* {
        void* p = (void*)(ws + off);
        off += (bytes + 255) & ~(size_t)255;
        return p;
    };
    float*  dis    = (float*)carve((size_t)N * 4);
    float4* xt     = (float4*)carve((size_t)N * 9 * 16);
    float4* agg0   = (float4*)carve((size_t)N * 9 * 16);
    float*  bufA   = (float*)carve((size_t)N * H100 * 4);
    float*  bufB   = (float*)carve((size_t)N * H100 * 4);
    float*  y      = (float*)carve((size_t)N * 4);
    int*    degi   = (int*)carve((size_t)N * 4);
    int*    rowptr = (int*)carve((size_t)(N + 1) * 4);
    int*    cursor = (int*)carve((size_t)N * 4);
    int*    srcidx = (int*)carve((size_t)E * 4);
    int*    bsum   = (int*)carve(1024 * 4);
    float*  sarr   = (float*)carve(4 * H100 * 4);
    float*  tarr   = (float*)carve(4 * H100 * 4);
    float*  wp     = (float*)carve(H100 * 4);
    float*  c3     = (float*)carve(256);
    float*  Wpad   = (float*)carve(36 * H100 * 4);
    float*  gacc   = (float*)carve((size_t)G * 4);

    const int nb_n  = (N + 255) / 256;
    const int nb_g  = (N + 63) / 64;
    const int nb_9  = (N * 9 + 255) / 256;
    const int nb_ga = (N + 9) / 10;
    const int npb   = (N + NBKT - 1) / NBKT;            // nodes per bucket
    const int chunk = (E + NSLICE - 1) / NSLICE;        // edges per slice
    const int nb_bkt = NBKT * NSLICE;

    // ---- CSR + params ----
    hipMemsetAsync(degi, 0, (size_t)N * 4, stream);
    deg_bucket_kernel<<<nb_bkt, 256, 0, stream>>>(colp, degi, E, npb, chunk);
    scan1_kernel<<<nb_n, 256, 0, stream>>>(degi, rowptr, bsum, N);
    scan2_kernel<<<1, 1024, 0, stream>>>(bsum, nb_n);
    scan3_kernel<<<nb_n, 256, 0, stream>>>(rowptr, bsum, degi, dis, cursor, N);
    fill_bucket_kernel<<<nb_bkt, 256, 0, stream>>>(row, colp, cursor, srcidx, E, npb, chunk);
    prep_kernel<<<(40 * H100 + 255) / 256, 256, 0, stream>>>(biases, gamma, beta, bn_mean,
                                                             bn_var, W0, sarr, tarr, Wpad);
    headprep_kernel<<<1, 128, 0, stream>>>(Ws + 2 * H100 * H100, headW,
                                           sarr + 3 * H100, tarr + 3 * H100, wp, c3);
    xprep_kernel<<<nb_9, 256, 0, stream>>>(x, dis, xt, N);

    // ---- layer 0: aggregate x (33-dim), then GEMM 36->100 with BN+ReLU ----
    gather33_kernel<<<nb_9, 256, 0, stream>>>(rowptr, srcidx, xt, dis, agg0, N);
    gemm_kernel<36, 1><<<nb_g, 256, 0, stream>>>((const float*)agg0, Wpad, dis,
                                                 sarr, tarr, bufA, N);   // h1

    // ---- layer 1 ----
    gemm_kernel<H100, 0><<<nb_g, 256, 0, stream>>>(bufA, Ws, dis, nullptr, nullptr, bufB, N);
    gather100_kernel<0><<<nb_ga, 256, 0, stream>>>(rowptr, srcidx, (const float4*)bufB, dis,
                                                   sarr + H100, tarr + H100, nullptr,
                                                   (float4*)bufA, nullptr, N);

    // ---- layer 2 (+ fused rank-1 head projection) ----
    gemm_kernel<H100, 0><<<nb_g, 256, 0, stream>>>(bufA, Ws + H100 * H100, dis,
                                                   nullptr, nullptr, bufB, N);
    gather100_kernel<1><<<nb_ga, 256, 0, stream>>>(rowptr, srcidx, (const float4*)bufB, dis,
                                                   sarr + 2 * H100, tarr + 2 * H100, wp,
                                                   nullptr, y, N);

    // ---- layer 3 collapsed to scalar gather + pool ----
    hipMemsetAsync(gacc, 0, (size_t)G * 4, stream);
    gather_scalar_kernel<<<nb_n, 256, 0, stream>>>(rowptr, srcidx, y, dis, c3, batch, gacc, N);
    finish_kernel<<<(G + 255) / 256, 256, 0, stream>>>(gacc, headb, out, G);
}

// Round 6
// 688.936 us; speedup vs baseline: 3.5402x; 1.0067x over previous
//
#include <hip/hip_runtime.h>
#include <hip/hip_bf16.h>

#define H100 100
#define BN_EPS 1e-5f
#define NBKT 8          // one bucket per XCD
#define NSLICE 200      // edge slices per bucket

// ================= bucketed degree count (XCD-local atomics) =================
__global__ __launch_bounds__(256) void deg_bucket_kernel(const int* __restrict__ col,
                                                         int* __restrict__ degi,
                                                         int E, int npb, int chunk) {
    const int bkt = blockIdx.x & (NBKT - 1);
    const int slice = blockIdx.x >> 3;
    const int lo = bkt * npb, hi = lo + npb;
    const int e0 = slice * chunk;
    const int e1 = (e0 + chunk < E) ? e0 + chunk : E;
    for (int e = e0 + threadIdx.x; e < e1; e += 256) {
        int c = col[e];
        if (c >= lo && c < hi) atomicAdd(&degi[c], 1);
    }
}

// ================= scan1 + fused parameter prep =================
// blocks [0,nbs): per-block inclusive scan of degi.
// block nbs: BN fold for all 4 layers, then wp = W3@(s3.*headW), c3 = t3.headW.
// blocks (nbs,nbs+23]: Wpad fill + gacc zero.
__global__ __launch_bounds__(256) void scan1_prep_kernel(
    const int* __restrict__ degi, int* __restrict__ rowptr, int* __restrict__ bsum, int n,
    int nbs,
    const float* __restrict__ b, const float* __restrict__ gamma,
    const float* __restrict__ beta, const float* __restrict__ mean,
    const float* __restrict__ var, const float* __restrict__ W0,
    const float* __restrict__ W3, const float* __restrict__ headW,
    float* __restrict__ sarr, float* __restrict__ tarr,
    float* __restrict__ Wpad, float* __restrict__ wp, float* __restrict__ c3,
    float* __restrict__ gacc, int G)
{
    const int t = threadIdx.x;
    if (blockIdx.x < nbs) {
        __shared__ int lds[256];
        const int gid = blockIdx.x * 256 + t;
        int v = (gid < n) ? degi[gid] : 0;
        lds[t] = v;
        __syncthreads();
        for (int off = 1; off < 256; off <<= 1) {
            int u = (t >= off) ? lds[t - off] : 0;
            __syncthreads();
            lds[t] += u;
            __syncthreads();
        }
        if (gid < n) rowptr[gid + 1] = lds[t];
        if (t == 255) bsum[blockIdx.x] = lds[t];
        return;
    }
    if (blockIdx.x == nbs) {
        // phase 1: BN fold (400 elems)
        __shared__ float ws_[H100];
        for (int idx = t; idx < 4 * H100; idx += 256) {
            float s = gamma[idx] * rsqrtf(var[idx] + BN_EPS);
            sarr[idx] = s;
            tarr[idx] = (b[idx] - mean[idx]) * s + beta[idx];
        }
        __syncthreads();
        // phase 2: rank-1 head fold
        if (t < H100) ws_[t] = sarr[3 * H100 + t] * headW[t];
        __syncthreads();
        if (t < H100) {
            float acc = 0.f;
            for (int c = 0; c < H100; ++c) acc += W3[t * H100 + c] * ws_[c];
            wp[t] = acc;
        }
        if (t == 0) {
            float acc = 0.f;
            for (int c = 0; c < H100; ++c) acc += tarr[3 * H100 + c] * headW[c];
            *c3 = acc;
        }
        return;
    }
    // remaining blocks: Wpad (3600) then gacc zero (G)
    int idx = (blockIdx.x - nbs - 1) * 256 + t;
    if (idx < 36 * H100) {
        Wpad[idx] = (idx < 33 * H100) ? W0[idx] : 0.f;
    } else {
        int gidx = idx - 36 * H100;
        if (gidx < G) gacc[gidx] = 0.f;
    }
}

__global__ __launch_bounds__(1024) void scan2_kernel(int* __restrict__ bsum, int nb) {
    __shared__ int lds[1024];
    const int t = threadIdx.x;
    int v = (t < nb) ? bsum[t] : 0;
    lds[t] = v;
    __syncthreads();
    for (int off = 1; off < 1024; off <<= 1) {
        int u = (t >= off) ? lds[t - off] : 0;
        __syncthreads();
        lds[t] += u;
        __syncthreads();
    }
    if (t < nb) bsum[t] = lds[t] - v;   // exclusive
}

__global__ __launch_bounds__(256) void scan3_kernel(int* __restrict__ rowptr,
                                                    const int* __restrict__ bsum,
                                                    const int* __restrict__ degi,
                                                    float* __restrict__ dis,
                                                    int* __restrict__ cursor, int n) {
    const int gid = blockIdx.x * 256 + threadIdx.x;
    if (gid >= n) return;
    const int d = degi[gid];
    const int rp1 = rowptr[gid + 1] + bsum[blockIdx.x];
    rowptr[gid + 1] = rp1;
    cursor[gid] = rp1 - d;
    if (gid == 0) rowptr[0] = 0;
    dis[gid] = rsqrtf((float)(d + 1));
}

// ================= fill (bucketed) + xprep fused (independent work) ==========
// blocks [0,nbf): CSR fill (XCD-local). blocks >= nbf: xprep (streaming, overlaps).
__global__ __launch_bounds__(256) void fill_xprep_kernel(
    const int* __restrict__ row, const int* __restrict__ col,
    int* __restrict__ cursor, int* __restrict__ srcidx,
    int E, int npb, int chunk, int nbf,
    const float* __restrict__ x, const float* __restrict__ dis,
    float4* __restrict__ xt, int n)
{
    if (blockIdx.x < nbf) {
        const int bkt = blockIdx.x & (NBKT - 1);
        const int slice = blockIdx.x >> 3;
        const int lo = bkt * npb, hi = lo + npb;
        const int e0 = slice * chunk;
        const int e1 = (e0 + chunk < E) ? e0 + chunk : E;
        for (int e = e0 + threadIdx.x; e < e1; e += 256) {
            int c = col[e];
            if (c >= lo && c < hi) {
                int slot = atomicAdd(&cursor[c], 1);
                srcidx[slot] = row[e];
            }
        }
        return;
    }
    int t = (blockIdx.x - nbf) * 256 + threadIdx.x;
    int node = t / 9;
    if (node >= n) return;
    int q = t - node * 9;
    const float d = dis[node];
    float v[4];
    #pragma unroll
    for (int j = 0; j < 4; ++j) {
        int c = q * 4 + j;
        v[j] = (c < 33) ? x[node * 33 + c] * d : 0.f;
    }
    xt[node * 9 + q] = make_float4(v[0], v[1], v[2], v[3]);
}

// ================= gather 33-dim: agg0 = A_norm x (9 thr-groups/node) ==========
__global__ __launch_bounds__(256) void gather33_kernel(
    const int* __restrict__ rowptr, const int* __restrict__ srcidx,
    const float4* __restrict__ xt, const float* __restrict__ dis,
    float4* __restrict__ agg0, int n)
{
    const int t = blockIdx.x * 256 + threadIdx.x;
    const int node = t / 9;
    if (node >= n) return;
    const int q = t - node * 9;

    float4 a0 = xt[node * 9 + q];           // self-loop
    float4 a1 = make_float4(0.f, 0.f, 0.f, 0.f);
    const int i1 = rowptr[node + 1];
    int i = rowptr[node];
    for (; i + 7 < i1; i += 8) {
        float4 v0 = xt[srcidx[i] * 9 + q];
        float4 v1 = xt[srcidx[i + 1] * 9 + q];
        float4 v2 = xt[srcidx[i + 2] * 9 + q];
        float4 v3 = xt[srcidx[i + 3] * 9 + q];
        float4 v4 = xt[srcidx[i + 4] * 9 + q];
        float4 v5 = xt[srcidx[i + 5] * 9 + q];
        float4 v6 = xt[srcidx[i + 6] * 9 + q];
        float4 v7 = xt[srcidx[i + 7] * 9 + q];
        a0.x += (v0.x + v1.x) + (v2.x + v3.x); a1.x += (v4.x + v5.x) + (v6.x + v7.x);
        a0.y += (v0.y + v1.y) + (v2.y + v3.y); a1.y += (v4.y + v5.y) + (v6.y + v7.y);
        a0.z += (v0.z + v1.z) + (v2.z + v3.z); a1.z += (v4.z + v5.z) + (v6.z + v7.z);
        a0.w += (v0.w + v1.w) + (v2.w + v3.w); a1.w += (v4.w + v5.w) + (v6.w + v7.w);
    }
    for (; i + 3 < i1; i += 4) {
        float4 v0 = xt[srcidx[i] * 9 + q];
        float4 v1 = xt[srcidx[i + 1] * 9 + q];
        float4 v2 = xt[srcidx[i + 2] * 9 + q];
        float4 v3 = xt[srcidx[i + 3] * 9 + q];
        a0.x += (v0.x + v1.x) + (v2.x + v3.x);
        a0.y += (v0.y + v1.y) + (v2.y + v3.y);
        a0.z += (v0.z + v1.z) + (v2.z + v3.z);
        a0.w += (v0.w + v1.w) + (v2.w + v3.w);
    }
    for (; i < i1; ++i) {
        float4 v0 = xt[srcidx[i] * 9 + q];
        a0.x += v0.x; a0.y += v0.y; a0.z += v0.z; a0.w += v0.w;
    }
    const float d = dis[node];
    agg0[node * 9 + q] = make_float4((a0.x + a1.x) * d, (a0.y + a1.y) * d,
                                     (a0.z + a1.z) * d, (a0.w + a1.w) * d);
}

// ================= GEMM (node-major in/out) =================
template <int CIN, int EPI>
__global__ __launch_bounds__(256) void gemm_kernel(
    const float* __restrict__ hin, const float* __restrict__ W,
    const float* __restrict__ dis, const float* __restrict__ sarr,
    const float* __restrict__ tarr, float* __restrict__ hout, int n)
{
    constexpr int KH = (CIN + 1) / 2;
    __shared__ float Wl[KH * H100 + 32];
    __shared__ float hsT[CIN * 68];
    const int tid = threadIdx.x;
    const int node0 = blockIdx.x * 64;

    for (int idx = tid; idx < 64 * CIN; idx += 256) {
        int r = idx / CIN;
        int k = idx - r * CIN;
        int node = node0 + r;
        hsT[k * 68 + r] = (node < n) ? hin[node * CIN + k] : 0.0f;
    }

    const int tx = tid & 15;
    const int ty = tid >> 4;
    float acc0[4][4] = {{0.f}};
    float acc1[4][4] = {{0.f}};

    for (int p = 0; p < 2; ++p) {
        const int k0 = p * KH;
        const int kn = (CIN - k0 < KH) ? (CIN - k0) : KH;
        __syncthreads();
        for (int idx = tid; idx < kn * H100; idx += 256)
            Wl[idx] = W[k0 * H100 + idx];
        __syncthreads();
        for (int kk = 0; kk < kn; ++kk) {
            const float4 a  = *reinterpret_cast<const float4*>(&hsT[(k0 + kk) * 68 + ty * 4]);
            const float4 w0 = *reinterpret_cast<const float4*>(&Wl[kk * H100 + tx * 4]);
            const float4 w1 = *reinterpret_cast<const float4*>(&Wl[kk * H100 + 64 + tx * 4]);
            const float av[4]  = {a.x, a.y, a.z, a.w};
            const float w0v[4] = {w0.x, w0.y, w0.z, w0.w};
            const float w1v[4] = {w1.x, w1.y, w1.z, w1.w};
            #pragma unroll
            for (int ni = 0; ni < 4; ++ni)
                #pragma unroll
                for (int ci = 0; ci < 4; ++ci) {
                    acc0[ni][ci] += av[ni] * w0v[ci];
                    acc1[ni][ci] += av[ni] * w1v[ci];
                }
        }
    }

    float4 s0, s1, t0, t1;
    if (EPI == 1) {
        s0 = *reinterpret_cast<const float4*>(&sarr[tx * 4]);
        t0 = *reinterpret_cast<const float4*>(&tarr[tx * 4]);
        if (tx < 9) {
            s1 = *reinterpret_cast<const float4*>(&sarr[64 + tx * 4]);
            t1 = *reinterpret_cast<const float4*>(&tarr[64 + tx * 4]);
        }
    }

    #pragma unroll
    for (int ni = 0; ni < 4; ++ni) {
        const int node = node0 + ty * 4 + ni;
        if (node >= n) continue;
        float4 o0, o1;
        if (EPI == 0) {
            const float d = dis[node];
            o0 = make_float4(acc0[ni][0] * d, acc0[ni][1] * d, acc0[ni][2] * d, acc0[ni][3] * d);
            o1 = make_float4(acc1[ni][0] * d, acc1[ni][1] * d, acc1[ni][2] * d, acc1[ni][3] * d);
        } else {
            o0.x = fmaxf(acc0[ni][0] * s0.x + t0.x, 0.f);
            o0.y = fmaxf(acc0[ni][1] * s0.y + t0.y, 0.f);
            o0.z = fmaxf(acc0[ni][2] * s0.z + t0.z, 0.f);
            o0.w = fmaxf(acc0[ni][3] * s0.w + t0.w, 0.f);
            if (tx < 9) {
                o1.x = fmaxf(acc1[ni][0] * s1.x + t1.x, 0.f);
                o1.y = fmaxf(acc1[ni][1] * s1.y + t1.y, 0.f);
                o1.z = fmaxf(acc1[ni][2] * s1.z + t1.z, 0.f);
                o1.w = fmaxf(acc1[ni][3] * s1.w + t1.w, 0.f);
            }
        }
        *reinterpret_cast<float4*>(&hout[node * H100 + tx * 4]) = o0;
        if (tx < 9)
            *reinterpret_cast<float4*>(&hout[node * H100 + 64 + tx * 4]) = o1;
    }
}

// ================= gather 100-dim (25 thr/node, 10 nodes/block) ================
template <int MODE>
__global__ __launch_bounds__(256) void gather100_kernel(
    const int* __restrict__ rowptr, const int* __restrict__ srcidx,
    const float4* __restrict__ z4, const float* __restrict__ dis,
    const float* __restrict__ sarr, const float* __restrict__ tarr,
    const float* __restrict__ wp, float4* __restrict__ hout,
    float* __restrict__ y, int n)
{
    const int tid = threadIdx.x;
    const int node = blockIdx.x * 10 + tid / 25;
    const int q = tid % 25;
    const bool valid = (tid < 250) && (node < n);

    float4 a0 = make_float4(0.f, 0.f, 0.f, 0.f);
    float4 a1 = make_float4(0.f, 0.f, 0.f, 0.f);
    float dn = 0.f;
    if (valid) {
        a0 = z4[node * 25 + q];             // self-loop
        dn = dis[node];
        const int i1 = rowptr[node + 1];
        int i = rowptr[node];
        for (; i + 7 < i1; i += 8) {
            float4 v0 = z4[srcidx[i] * 25 + q];
            float4 v1 = z4[srcidx[i + 1] * 25 + q];
            float4 v2 = z4[srcidx[i + 2] * 25 + q];
            float4 v3 = z4[srcidx[i + 3] * 25 + q];
            float4 v4 = z4[srcidx[i + 4] * 25 + q];
            float4 v5 = z4[srcidx[i + 5] * 25 + q];
            float4 v6 = z4[srcidx[i + 6] * 25 + q];
            float4 v7 = z4[srcidx[i + 7] * 25 + q];
            a0.x += (v0.x + v1.x) + (v2.x + v3.x); a1.x += (v4.x + v5.x) + (v6.x + v7.x);
            a0.y += (v0.y + v1.y) + (v2.y + v3.y); a1.y += (v4.y + v5.y) + (v6.y + v7.y);
            a0.z += (v0.z + v1.z) + (v2.z + v3.z); a1.z += (v4.z + v5.z) + (v6.z + v7.z);
            a0.w += (v0.w + v1.w) + (v2.w + v3.w); a1.w += (v4.w + v5.w) + (v6.w + v7.w);
        }
        for (; i + 3 < i1; i += 4) {
            float4 v0 = z4[srcidx[i] * 25 + q];
            float4 v1 = z4[srcidx[i + 1] * 25 + q];
            float4 v2 = z4[srcidx[i + 2] * 25 + q];
            float4 v3 = z4[srcidx[i + 3] * 25 + q];
            a0.x += (v0.x + v1.x) + (v2.x + v3.x);
            a0.y += (v0.y + v1.y) + (v2.y + v3.y);
            a0.z += (v0.z + v1.z) + (v2.z + v3.z);
            a0.w += (v0.w + v1.w) + (v2.w + v3.w);
        }
        for (; i < i1; ++i) {
            float4 v0 = z4[srcidx[i] * 25 + q];
            a0.x += v0.x; a0.y += v0.y; a0.z += v0.z; a0.w += v0.w;
        }
    }
    float4 acc = make_float4(a0.x + a1.x, a0.y + a1.y, a0.z + a1.z, a0.w + a1.w);

    const float4 s  = *reinterpret_cast<const float4*>(&sarr[q * 4]);
    const float4 tt = *reinterpret_cast<const float4*>(&tarr[q * 4]);
    float4 hv;
    hv.x = fmaxf(acc.x * dn * s.x + tt.x, 0.f);
    hv.y = fmaxf(acc.y * dn * s.y + tt.y, 0.f);
    hv.z = fmaxf(acc.z * dn * s.z + tt.z, 0.f);
    hv.w = fmaxf(acc.w * dn * s.w + tt.w, 0.f);

    if (MODE == 0) {
        if (valid) hout[node * 25 + q] = hv;
    } else {
        const float4 w = *reinterpret_cast<const float4*>(&wp[q * 4]);
        float partial = hv.x * w.x + hv.y * w.y + hv.z * w.z + hv.w * w.w;
        __shared__ float red[256];
        red[tid] = valid ? partial : 0.f;
        __syncthreads();
        if (q == 0 && valid) {
            float sum = 0.f;
            #pragma unroll
            for (int j = 0; j < 25; ++j) sum += red[tid + j];
            y[node] = sum * dn;
        }
    }
}

// ================= scalar gather (layer 3 collapsed) + pool =================
__global__ __launch_bounds__(256) void gather_scalar_kernel(
    const int* __restrict__ rowptr, const int* __restrict__ srcidx,
    const float* __restrict__ y, const float* __restrict__ dis,
    const float* __restrict__ c3, const int* __restrict__ batch,
    float* __restrict__ gacc, int n)
{
    const int node = blockIdx.x * 256 + threadIdx.x;
    if (node >= n) return;
    float acc = y[node];
    float accb = 0.f;
    const int i1 = rowptr[node + 1];
    int i = rowptr[node];
    for (; i + 7 < i1; i += 8) {
        acc  += (y[srcidx[i]]     + y[srcidx[i + 1]]) + (y[srcidx[i + 2]] + y[srcidx[i + 3]]);
        accb += (y[srcidx[i + 4]] + y[srcidx[i + 5]]) + (y[srcidx[i + 6]] + y[srcidx[i + 7]]);
    }
    for (; i + 3 < i1; i += 4)
        acc += (y[srcidx[i]] + y[srcidx[i + 1]]) + (y[srcidx[i + 2]] + y[srcidx[i + 3]]);
    for (; i < i1; ++i) acc += y[srcidx[i]];
    unsafeAtomicAdd(&gacc[batch[node]], dis[node] * (acc + accb) + c3[0]);
}

__global__ __launch_bounds__(256) void finish_kernel(const float* __restrict__ gacc,
                                                     const float* __restrict__ hb,
                                                     float* __restrict__ out, int G) {
    int g = blockIdx.x * 256 + threadIdx.x;
    if (g >= G) return;
    float o = gacc[g] + hb[0];
    out[g] = (o >= 0.f) ? o : 0.1f * o;
}

extern "C" void kernel_launch(void* const* d_in, const int* in_sizes, int n_in,
                              void* d_out, int out_size, void* d_ws, size_t ws_size,
                              hipStream_t stream) {
    const float* x       = (const float*)d_in[0];
    const int*   ei      = (const int*)d_in[1];
    const int*   batch   = (const int*)d_in[2];
    const float* W0      = (const float*)d_in[3];
    const float* Ws      = (const float*)d_in[4];
    const float* biases  = (const float*)d_in[5];
    const float* gamma   = (const float*)d_in[6];
    const float* beta    = (const float*)d_in[7];
    const float* bn_mean = (const float*)d_in[8];
    const float* bn_var  = (const float*)d_in[9];
    const float* headW   = (const float*)d_in[10];
    const float* headb   = (const float*)d_in[11];
    float* out = (float*)d_out;

    const int N = in_sizes[2];
    const int E = in_sizes[1] / 2;
    const int G = out_size;
    const int* row  = ei;
    const int* colp = ei + E;

    char* ws = (char*)d_ws;
    size_t off = 0;
    auto carve = [&](size_t bytes) -> void* {
        void* p = (void*)(ws + off);
        off += (bytes + 255) & ~(size_t)255;
        return p;
    };
    float*  dis    = (float*)carve((size_t)N * 4);
    float4* xt     = (float4*)carve((size_t)N * 9 * 16);
    float4* agg0   = (float4*)carve((size_t)N * 9 * 16);
    float*  bufA   = (float*)carve((size_t)N * H100 * 4);
    float*  bufB   = (float*)carve((size_t)N * H100 * 4);
    float*  y      = (float*)carve((size_t)N * 4);
    int*    degi   = (int*)carve((size_t)N * 4);
    int*    rowptr = (int*)carve((size_t)(N + 1) * 4);
    int*    cursor = (int*)carve((size_t)N * 4);
    int*    srcidx = (int*)carve((size_t)E * 4);
    int*    bsum   = (int*)carve(1024 * 4);
    float*  sarr   = (float*)carve(4 * H100 * 4);
    float*  tarr   = (float*)carve(4 * H100 * 4);
    float*  wp     = (float*)carve(H100 * 4);
    float*  c3     = (float*)carve(256);
    float*  Wpad   = (float*)carve(36 * H100 * 4);
    float*  gacc   = (float*)carve((size_t)G * 4);

    const int nb_n  = (N + 255) / 256;          // scan blocks
    const int nb_g  = (N + 63) / 64;
    const int nb_9  = (N * 9 + 255) / 256;
    const int nb_ga = (N + 9) / 10;
    const int npb   = (N + NBKT - 1) / NBKT;
    const int chunk = (E + NSLICE - 1) / NSLICE;
    const int nb_bkt = NBKT * NSLICE;
    const int nb_pad = (36 * H100 + G + 255) / 256;   // Wpad + gacc-zero blocks

    // ---- CSR + params ----
    hipMemsetAsync(degi, 0, (size_t)N * 4, stream);
    deg_bucket_kernel<<<nb_bkt, 256, 0, stream>>>(colp, degi, E, npb, chunk);
    scan1_prep_kernel<<<nb_n + 1 + nb_pad, 256, 0, stream>>>(
        degi, rowptr, bsum, N, nb_n,
        biases, gamma, beta, bn_mean, bn_var, W0,
        Ws + 2 * H100 * H100, headW, sarr, tarr, Wpad, wp, c3, gacc, G);
    scan2_kernel<<<1, 1024, 0, stream>>>(bsum, nb_n);
    scan3_kernel<<<nb_n, 256, 0, stream>>>(rowptr, bsum, degi, dis, cursor, N);
    fill_xprep_kernel<<<nb_bkt + nb_9, 256, 0, stream>>>(row, colp, cursor, srcidx,
                                                         E, npb, chunk, nb_bkt,
                                                         x, dis, xt, N);

    // ---- layer 0: aggregate x (33-dim), then GEMM 36->100 with BN+ReLU ----
    gather33_kernel<<<nb_9, 256, 0, stream>>>(rowptr, srcidx, xt, dis, agg0, N);
    gemm_kernel<36, 1><<<nb_g, 256, 0, stream>>>((const float*)agg0, Wpad, dis,
                                                 sarr, tarr, bufA, N);   // h1

    // ---- layer 1 ----
    gemm_kernel<H100, 0><<<nb_g, 256, 0, stream>>>(bufA, Ws, dis, nullptr, nullptr, bufB, N);
    gather100_kernel<0><<<nb_ga, 256, 0, stream>>>(rowptr, srcidx, (const float4*)bufB, dis,
                                                   sarr + H100, tarr + H100, nullptr,
                                                   (float4*)bufA, nullptr, N);

    // ---- layer 2 (+ fused rank-1 head projection) ----
    gemm_kernel<H100, 0><<<nb_g, 256, 0, stream>>>(bufA, Ws + H100 * H100, dis,
                                                   nullptr, nullptr, bufB, N);
    gather100_kernel<1><<<nb_ga, 256, 0, stream>>>(rowptr, srcidx, (const float4*)bufB, dis,
                                                   sarr + 2 * H100, tarr + 2 * H100, wp,
                                                   nullptr, y, N);

    // ---- layer 3 collapsed to scalar gather + pool ----
    gather_scalar_kernel<<<nb_n, 256, 0, stream>>>(rowptr, srcidx, y, dis, c3, batch, gacc, N);
    finish_kernel<<<(G + 255) / 256, 256, 0, stream>>>(gacc, headb, out, G);
}

// Round 7
// 688.370 us; speedup vs baseline: 3.5431x; 1.0008x over previous
//
#include <hip/hip_runtime.h>
#include <hip/hip_bf16.h>

#define H100 100
#define BN_EPS 1e-5f
#define NBKT 8          // dest buckets = XCDs
#define NSLICE 200      // edge slices per dest bucket
#define SRCSH 13        // source-bucket shift: 8192 nodes = 3.2MB of xw per bucket

// ======== histogram of (dest, src-bucket) counts, XCD-local atomics ========
__global__ __launch_bounds__(256) void hist_bucket_kernel(const int* __restrict__ row,
                                                          const int* __restrict__ col,
                                                          int* __restrict__ segc,
                                                          int E, int npb, int chunk, int n) {
    const int bkt = blockIdx.x & (NBKT - 1);
    const int slice = blockIdx.x >> 3;
    const int lo = bkt * npb, hi = lo + npb;
    const int e0 = slice * chunk;
    const int e1 = (e0 + chunk < E) ? e0 + chunk : E;
    for (int e = e0 + threadIdx.x; e < e1; e += 256) {
        int c = col[e];
        if (c >= lo && c < hi) {
            int sb = row[e] >> SRCSH;
            atomicAdd(&segc[sb * n + c], 1);
        }
    }
}

// ================= scan1 + fused parameter prep =================
__global__ __launch_bounds__(256) void scan1_prep_kernel(
    const int* __restrict__ segc, int* __restrict__ degi,
    int* __restrict__ rowptr, int* __restrict__ bsum, int n, int nb2,
    int nbs,
    const float* __restrict__ b, const float* __restrict__ gamma,
    const float* __restrict__ beta, const float* __restrict__ mean,
    const float* __restrict__ var, const float* __restrict__ W0,
    const float* __restrict__ W3, const float* __restrict__ headW,
    float* __restrict__ sarr, float* __restrict__ tarr,
    float* __restrict__ Wpad, float* __restrict__ wp, float* __restrict__ c3,
    float* __restrict__ gacc, int G)
{
    const int t = threadIdx.x;
    if (blockIdx.x < nbs) {
        __shared__ int lds[256];
        const int gid = blockIdx.x * 256 + t;
        int v = 0;
        if (gid < n) {
            for (int bb = 0; bb < nb2; ++bb) v += segc[bb * n + gid];
            degi[gid] = v;
        }
        lds[t] = v;
        __syncthreads();
        for (int off = 1; off < 256; off <<= 1) {
            int u = (t >= off) ? lds[t - off] : 0;
            __syncthreads();
            lds[t] += u;
            __syncthreads();
        }
        if (gid < n) rowptr[gid + 1] = lds[t];
        if (t == 255) bsum[blockIdx.x] = lds[t];
        return;
    }
    if (blockIdx.x == nbs) {
        __shared__ float ws_[H100];
        for (int idx = t; idx < 4 * H100; idx += 256) {
            float s = gamma[idx] * rsqrtf(var[idx] + BN_EPS);
            sarr[idx] = s;
            tarr[idx] = (b[idx] - mean[idx]) * s + beta[idx];
        }
        __syncthreads();
        if (t < H100) ws_[t] = sarr[3 * H100 + t] * headW[t];
        __syncthreads();
        if (t < H100) {
            float acc = 0.f;
            for (int c = 0; c < H100; ++c) acc += W3[t * H100 + c] * ws_[c];
            wp[t] = acc;
        }
        if (t == 0) {
            float acc = 0.f;
            for (int c = 0; c < H100; ++c) acc += tarr[3 * H100 + c] * headW[c];
            *c3 = acc;
        }
        return;
    }
    int idx = (blockIdx.x - nbs - 1) * 256 + t;
    if (idx < 36 * H100) {
        Wpad[idx] = (idx < 33 * H100) ? W0[idx] : 0.f;
    } else {
        int gidx = idx - 36 * H100;
        if (gidx < G) gacc[gidx] = 0.f;
    }
}

__global__ __launch_bounds__(1024) void scan2_kernel(int* __restrict__ bsum, int nb) {
    __shared__ int lds[1024];
    const int t = threadIdx.x;
    int v = (t < nb) ? bsum[t] : 0;
    lds[t] = v;
    __syncthreads();
    for (int off = 1; off < 1024; off <<= 1) {
        int u = (t >= off) ? lds[t - off] : 0;
        __syncthreads();
        lds[t] += u;
        __syncthreads();
    }
    if (t < nb) bsum[t] = lds[t] - v;   // exclusive
}

// finalize rowptr, dis; convert segc counts -> per-(node,bucket) start cursors
__global__ __launch_bounds__(256) void scan3_kernel(int* __restrict__ rowptr,
                                                    const int* __restrict__ bsum,
                                                    const int* __restrict__ degi,
                                                    float* __restrict__ dis,
                                                    int* __restrict__ segc,
                                                    int n, int nb2) {
    const int gid = blockIdx.x * 256 + threadIdx.x;
    if (gid >= n) return;
    const int d = degi[gid];
    const int rp1 = rowptr[gid + 1] + bsum[blockIdx.x];
    rowptr[gid + 1] = rp1;
    if (gid == 0) rowptr[0] = 0;
    dis[gid] = rsqrtf((float)(d + 1));
    int c = rp1 - d;
    for (int bb = 0; bb < nb2; ++bb) {
        int cnt = segc[bb * n + gid];
        segc[bb * n + gid] = c;
        c += cnt;
    }
}

// ======== segmented fill (bucketed by dest XCD) + xprep fused ========
__global__ __launch_bounds__(256) void fill_xprep_kernel(
    const int* __restrict__ row, const int* __restrict__ col,
    int* __restrict__ segc, int* __restrict__ srcidx,
    int E, int npb, int chunk, int nbf,
    const float* __restrict__ x, const float* __restrict__ dis,
    float4* __restrict__ xt, int n)
{
    if (blockIdx.x < nbf) {
        const int bkt = blockIdx.x & (NBKT - 1);
        const int slice = blockIdx.x >> 3;
        const int lo = bkt * npb, hi = lo + npb;
        const int e0 = slice * chunk;
        const int e1 = (e0 + chunk < E) ? e0 + chunk : E;
        for (int e = e0 + threadIdx.x; e < e1; e += 256) {
            int c = col[e];
            if (c >= lo && c < hi) {
                int r0 = row[e];
                int slot = atomicAdd(&segc[(r0 >> SRCSH) * n + c], 1);
                srcidx[slot] = r0;
            }
        }
        return;
    }
    int t = (blockIdx.x - nbf) * 256 + threadIdx.x;
    int node = t / 9;
    if (node >= n) return;
    int q = t - node * 9;
    const float d = dis[node];
    float v[4];
    #pragma unroll
    for (int j = 0; j < 4; ++j) {
        int c = q * 4 + j;
        v[j] = (c < 33) ? x[node * 33 + c] * d : 0.f;
    }
    xt[node * 9 + q] = make_float4(v[0], v[1], v[2], v[3]);
}

// ================= gather 33-dim (flat; lists bucket-grouped) =================
__global__ __launch_bounds__(256) void gather33_kernel(
    const int* __restrict__ rowptr, const int* __restrict__ srcidx,
    const float4* __restrict__ xt, const float* __restrict__ dis,
    float4* __restrict__ agg0, int n)
{
    const int t = blockIdx.x * 256 + threadIdx.x;
    const int node = t / 9;
    if (node >= n) return;
    const int q = t - node * 9;

    float4 a0 = xt[node * 9 + q];
    float4 a1 = make_float4(0.f, 0.f, 0.f, 0.f);
    const int i1 = rowptr[node + 1];
    int i = rowptr[node];
    for (; i + 3 < i1; i += 4) {
        float4 v0 = xt[srcidx[i] * 9 + q];
        float4 v1 = xt[srcidx[i + 1] * 9 + q];
        float4 v2 = xt[srcidx[i + 2] * 9 + q];
        float4 v3 = xt[srcidx[i + 3] * 9 + q];
        a0.x += (v0.x + v1.x) + (v2.x + v3.x);
        a0.y += (v0.y + v1.y) + (v2.y + v3.y);
        a0.z += (v0.z + v1.z) + (v2.z + v3.z);
        a0.w += (v0.w + v1.w) + (v2.w + v3.w);
    }
    for (; i < i1; ++i) {
        float4 v0 = xt[srcidx[i] * 9 + q];
        a1.x += v0.x; a1.y += v0.y; a1.z += v0.z; a1.w += v0.w;
    }
    const float d = dis[node];
    agg0[node * 9 + q] = make_float4((a0.x + a1.x) * d, (a0.y + a1.y) * d,
                                     (a0.z + a1.z) * d, (a0.w + a1.w) * d);
}

// ================= GEMM (node-major in/out) =================
template <int CIN, int EPI>
__global__ __launch_bounds__(256) void gemm_kernel(
    const float* __restrict__ hin, const float* __restrict__ W,
    const float* __restrict__ dis, const float* __restrict__ sarr,
    const float* __restrict__ tarr, float* __restrict__ hout, int n)
{
    constexpr int KH = (CIN + 1) / 2;
    __shared__ float Wl[KH * H100 + 32];
    __shared__ float hsT[CIN * 68];
    const int tid = threadIdx.x;
    const int node0 = blockIdx.x * 64;

    for (int idx = tid; idx < 64 * CIN; idx += 256) {
        int r = idx / CIN;
        int k = idx - r * CIN;
        int node = node0 + r;
        hsT[k * 68 + r] = (node < n) ? hin[node * CIN + k] : 0.0f;
    }

    const int tx = tid & 15;
    const int ty = tid >> 4;
    float acc0[4][4] = {{0.f}};
    float acc1[4][4] = {{0.f}};

    for (int p = 0; p < 2; ++p) {
        const int k0 = p * KH;
        const int kn = (CIN - k0 < KH) ? (CIN - k0) : KH;
        __syncthreads();
        for (int idx = tid; idx < kn * H100; idx += 256)
            Wl[idx] = W[k0 * H100 + idx];
        __syncthreads();
        for (int kk = 0; kk < kn; ++kk) {
            const float4 a  = *reinterpret_cast<const float4*>(&hsT[(k0 + kk) * 68 + ty * 4]);
            const float4 w0 = *reinterpret_cast<const float4*>(&Wl[kk * H100 + tx * 4]);
            const float4 w1 = *reinterpret_cast<const float4*>(&Wl[kk * H100 + 64 + tx * 4]);
            const float av[4]  = {a.x, a.y, a.z, a.w};
            const float w0v[4] = {w0.x, w0.y, w0.z, w0.w};
            const float w1v[4] = {w1.x, w1.y, w1.z, w1.w};
            #pragma unroll
            for (int ni = 0; ni < 4; ++ni)
                #pragma unroll
                for (int ci = 0; ci < 4; ++ci) {
                    acc0[ni][ci] += av[ni] * w0v[ci];
                    acc1[ni][ci] += av[ni] * w1v[ci];
                }
        }
    }

    float4 s0, s1, t0, t1;
    if (EPI == 1) {
        s0 = *reinterpret_cast<const float4*>(&sarr[tx * 4]);
        t0 = *reinterpret_cast<const float4*>(&tarr[tx * 4]);
        if (tx < 9) {
            s1 = *reinterpret_cast<const float4*>(&sarr[64 + tx * 4]);
            t1 = *reinterpret_cast<const float4*>(&tarr[64 + tx * 4]);
        }
    }

    #pragma unroll
    for (int ni = 0; ni < 4; ++ni) {
        const int node = node0 + ty * 4 + ni;
        if (node >= n) continue;
        float4 o0, o1;
        if (EPI == 0) {
            const float d = dis[node];
            o0 = make_float4(acc0[ni][0] * d, acc0[ni][1] * d, acc0[ni][2] * d, acc0[ni][3] * d);
            o1 = make_float4(acc1[ni][0] * d, acc1[ni][1] * d, acc1[ni][2] * d, acc1[ni][3] * d);
        } else {
            o0.x = fmaxf(acc0[ni][0] * s0.x + t0.x, 0.f);
            o0.y = fmaxf(acc0[ni][1] * s0.y + t0.y, 0.f);
            o0.z = fmaxf(acc0[ni][2] * s0.z + t0.z, 0.f);
            o0.w = fmaxf(acc0[ni][3] * s0.w + t0.w, 0.f);
            if (tx < 9) {
                o1.x = fmaxf(acc1[ni][0] * s1.x + t1.x, 0.f);
                o1.y = fmaxf(acc1[ni][1] * s1.y + t1.y, 0.f);
                o1.z = fmaxf(acc1[ni][2] * s1.z + t1.z, 0.f);
                o1.w = fmaxf(acc1[ni][3] * s1.w + t1.w, 0.f);
            }
        }
        *reinterpret_cast<float4*>(&hout[node * H100 + tx * 4]) = o0;
        if (tx < 9)
            *reinterpret_cast<float4*>(&hout[node * H100 + 64 + tx * 4]) = o1;
    }
}

// ========== bucket-synchronized persistent gather 100-dim ==========
// grid = ceil(N/50) blocks (~co-resident). 10 groups x 25 threads; each group
// owns 5 nodes, accumulators in registers. Outer loop over source buckets:
// all resident waves read the same 3.2MB xw window -> L2-resident.
template <int MODE>
__global__ __launch_bounds__(256) void gather100s_kernel(
    const int* __restrict__ rowptr, const int* __restrict__ srcidx,
    const int* __restrict__ segc,   // post-fill: end cursor of (bucket,node) segment
    const float4* __restrict__ z4, const float* __restrict__ dis,
    const float* __restrict__ sarr, const float* __restrict__ tarr,
    const float* __restrict__ wp, float4* __restrict__ hout,
    float* __restrict__ y, int n, int nb2)
{
    const int tid = threadIdx.x;
    const int g = tid / 25;          // 0..9 active, 10 = idle tail
    const int q = tid - g * 25;
    const bool act = (g < 10);
    const int base = blockIdx.x * 50 + g * 5;
    const int blk0 = blockIdx.x * 50;

    __shared__ int ends[64];
    __shared__ float red[256];

    float4 acc[5];
    int cur[5];
    #pragma unroll
    for (int k = 0; k < 5; ++k) {
        const int node = base + k;
        const bool v = act && node < n;
        acc[k] = v ? z4[node * 25 + q] : make_float4(0.f, 0.f, 0.f, 0.f);
        cur[k] = v ? rowptr[node] : 0;
    }

    for (int b = 0; b < nb2; ++b) {
        __syncthreads();
        if (tid < 50) {
            const int node = blk0 + tid;
            ends[tid] = (node < n) ? segc[b * n + node] : 0;
        }
        __syncthreads();
        if (act) {
            #pragma unroll
            for (int k = 0; k < 5; ++k) {
                const int e1 = ends[g * 5 + k];
                int i = cur[k];
                for (; i + 1 < e1; i += 2) {
                    const float4 v0 = z4[srcidx[i] * 25 + q];
                    const float4 v1 = z4[srcidx[i + 1] * 25 + q];
                    acc[k].x += v0.x + v1.x; acc[k].y += v0.y + v1.y;
                    acc[k].z += v0.z + v1.z; acc[k].w += v0.w + v1.w;
                }
                if (i < e1) {
                    const float4 v0 = z4[srcidx[i] * 25 + q];
                    acc[k].x += v0.x; acc[k].y += v0.y; acc[k].z += v0.z; acc[k].w += v0.w;
                }
                cur[k] = e1;
            }
        }
    }

    const float4 s  = *reinterpret_cast<const float4*>(&sarr[q * 4]);
    const float4 tt = *reinterpret_cast<const float4*>(&tarr[q * 4]);

    if (MODE == 0) {
        #pragma unroll
        for (int k = 0; k < 5; ++k) {
            const int node = base + k;
            if (!act || node >= n) continue;
            const float dn = dis[node];
            float4 hv;
            hv.x = fmaxf(acc[k].x * dn * s.x + tt.x, 0.f);
            hv.y = fmaxf(acc[k].y * dn * s.y + tt.y, 0.f);
            hv.z = fmaxf(acc[k].z * dn * s.z + tt.z, 0.f);
            hv.w = fmaxf(acc[k].w * dn * s.w + tt.w, 0.f);
            hout[node * 25 + q] = hv;
        }
    } else {
        const float4 w = *reinterpret_cast<const float4*>(&wp[q * 4]);
        #pragma unroll
        for (int k = 0; k < 5; ++k) {
            const int node = base + k;
            float partial = 0.f;
            float dn = 0.f;
            if (act && node < n) {
                dn = dis[node];
                float4 hv;
                hv.x = fmaxf(acc[k].x * dn * s.x + tt.x, 0.f);
                hv.y = fmaxf(acc[k].y * dn * s.y + tt.y, 0.f);
                hv.z = fmaxf(acc[k].z * dn * s.z + tt.z, 0.f);
                hv.w = fmaxf(acc[k].w * dn * s.w + tt.w, 0.f);
                partial = hv.x * w.x + hv.y * w.y + hv.z * w.z + hv.w * w.w;
            }
            red[tid] = partial;
            __syncthreads();
            if (act && q == 0 && node < n) {
                float sum = 0.f;
                #pragma unroll
                for (int j = 0; j < 25; ++j) sum += red[g * 25 + j];
                y[node] = sum * dn;
            }
            __syncthreads();
        }
    }
}

// ================= scalar gather (layer 3 collapsed) + pool =================
__global__ __launch_bounds__(256) void gather_scalar_kernel(
    const int* __restrict__ rowptr, const int* __restrict__ srcidx,
    const float* __restrict__ y, const float* __restrict__ dis,
    const float* __restrict__ c3, const int* __restrict__ batch,
    float* __restrict__ gacc, int n)
{
    const int node = blockIdx.x * 256 + threadIdx.x;
    if (node >= n) return;
    float acc = y[node];
    const int i1 = rowptr[node + 1];
    int i = rowptr[node];
    for (; i + 3 < i1; i += 4)
        acc += (y[srcidx[i]] + y[srcidx[i + 1]]) + (y[srcidx[i + 2]] + y[srcidx[i + 3]]);
    for (; i < i1; ++i) acc += y[srcidx[i]];
    unsafeAtomicAdd(&gacc[batch[node]], dis[node] * acc + c3[0]);
}

__global__ __launch_bounds__(256) void finish_kernel(const float* __restrict__ gacc,
                                                     const float* __restrict__ hb,
                                                     float* __restrict__ out, int G) {
    int g = blockIdx.x * 256 + threadIdx.x;
    if (g >= G) return;
    float o = gacc[g] + hb[0];
    out[g] = (o >= 0.f) ? o : 0.1f * o;
}

extern "C" void kernel_launch(void* const* d_in, const int* in_sizes, int n_in,
                              void* d_out, int out_size, void* d_ws, size_t ws_size,
                              hipStream_t stream) {
    const float* x       = (const float*)d_in[0];
    const int*   ei      = (const int*)d_in[1];
    const int*   batch   = (const int*)d_in[2];
    const float* W0      = (const float*)d_in[3];
    const float* Ws      = (const float*)d_in[4];
    const float* biases  = (const float*)d_in[5];
    const float* gamma   = (const float*)d_in[6];
    const float* beta    = (const float*)d_in[7];
    const float* bn_mean = (const float*)d_in[8];
    const float* bn_var  = (const float*)d_in[9];
    const float* headW   = (const float*)d_in[10];
    const float* headb   = (const float*)d_in[11];
    float* out = (float*)d_out;

    const int N = in_sizes[2];
    const int E = in_sizes[1] / 2;
    const int G = out_size;
    const int* row  = ei;
    const int* colp = ei + E;
    const int nb2 = (N + (1 << SRCSH) - 1) >> SRCSH;   // source buckets (13 @ N=100k)

    char* ws = (char*)d_ws;
    size_t off = 0;
    auto carve = [&](size_t bytes) -> void* {
        void* p = (void*)(ws + off);
        off += (bytes + 255) & ~(size_t)255;
        return p;
    };
    float*  dis    = (float*)carve((size_t)N * 4);
    float4* xt     = (float4*)carve((size_t)N * 9 * 16);
    float4* agg0   = (float4*)carve((size_t)N * 9 * 16);
    float*  bufA   = (float*)carve((size_t)N * H100 * 4);
    float*  bufB   = (float*)carve((size_t)N * H100 * 4);
    float*  y      = (float*)carve((size_t)N * 4);
    int*    degi   = (int*)carve((size_t)N * 4);
    int*    rowptr = (int*)carve((size_t)(N + 1) * 4);
    int*    segc   = (int*)carve((size_t)nb2 * N * 4);
    int*    srcidx = (int*)carve((size_t)E * 4);
    int*    bsum   = (int*)carve(1024 * 4);
    float*  sarr   = (float*)carve(4 * H100 * 4);
    float*  tarr   = (float*)carve(4 * H100 * 4);
    float*  wp     = (float*)carve(H100 * 4);
    float*  c3     = (float*)carve(256);
    float*  Wpad   = (float*)carve(36 * H100 * 4);
    float*  gacc   = (float*)carve((size_t)G * 4);

    const int nb_n  = (N + 255) / 256;
    const int nb_g  = (N + 63) / 64;
    const int nb_9  = (N * 9 + 255) / 256;
    const int nb_gs = (N + 49) / 50;                 // persistent gather blocks
    const int npb   = (N + NBKT - 1) / NBKT;
    const int chunk = (E + NSLICE - 1) / NSLICE;
    const int nb_bkt = NBKT * NSLICE;
    const int nb_pad = (36 * H100 + G + 255) / 256;

    // ---- CSR (source-bucket-segmented) + params ----
    hipMemsetAsync(segc, 0, (size_t)nb2 * N * 4, stream);
    hist_bucket_kernel<<<nb_bkt, 256, 0, stream>>>(row, colp, segc, E, npb, chunk, N);
    scan1_prep_kernel<<<nb_n + 1 + nb_pad, 256, 0, stream>>>(
        segc, degi, rowptr, bsum, N, nb2, nb_n,
        biases, gamma, beta, bn_mean, bn_var, W0,
        Ws + 2 * H100 * H100, headW, sarr, tarr, Wpad, wp, c3, gacc, G);
    scan2_kernel<<<1, 1024, 0, stream>>>(bsum, nb_n);
    scan3_kernel<<<nb_n, 256, 0, stream>>>(rowptr, bsum, degi, dis, segc, N, nb2);
    fill_xprep_kernel<<<nb_bkt + nb_9, 256, 0, stream>>>(row, colp, segc, srcidx,
                                                         E, npb, chunk, nb_bkt,
                                                         x, dis, xt, N);

    // ---- layer 0: aggregate x (33-dim), then GEMM 36->100 with BN+ReLU ----
    gather33_kernel<<<nb_9, 256, 0, stream>>>(rowptr, srcidx, xt, dis, agg0, N);
    gemm_kernel<36, 1><<<nb_g, 256, 0, stream>>>((const float*)agg0, Wpad, dis,
                                                 sarr, tarr, bufA, N);   // h1

    // ---- layer 1 ----
    gemm_kernel<H100, 0><<<nb_g, 256, 0, stream>>>(bufA, Ws, dis, nullptr, nullptr, bufB, N);
    gather100s_kernel<0><<<nb_gs, 256, 0, stream>>>(rowptr, srcidx, segc,
                                                    (const float4*)bufB, dis,
                                                    sarr + H100, tarr + H100, nullptr,
                                                    (float4*)bufA, nullptr, N, nb2);

    // ---- layer 2 (+ fused rank-1 head projection) ----
    gemm_kernel<H100, 0><<<nb_g, 256, 0, stream>>>(bufA, Ws + H100 * H100, dis,
                                                   nullptr, nullptr, bufB, N);
    gather100s_kernel<1><<<nb_gs, 256, 0, stream>>>(rowptr, srcidx, segc,
                                                    (const float4*)bufB, dis,
                                                    sarr + 2 * H100, tarr + 2 * H100, wp,
                                                    nullptr, y, N, nb2);

    // ---- layer 3 collapsed to scalar gather + pool ----
    gather_scalar_kernel<<<nb_n, 256, 0, stream>>>(rowptr, srcidx, y, dis, c3, batch, gacc, N);
    finish_kernel<<<(G + 255) / 256, 256, 0, stream>>>(gacc, headb, out, G);
}

// Round 8
// 649.291 us; speedup vs baseline: 3.7564x; 1.0602x over previous
//
#include <hip/hip_runtime.h>
#include <hip/hip_bf16.h>

#define H100 100
#define BN_EPS 1e-5f
#define NBKT 8          // dest buckets = XCDs
#define NSLICE 200      // edge slices per dest bucket

// ================= bucketed degree count (XCD-local atomics) =================
__global__ __launch_bounds__(256) void deg_bucket_kernel(const int* __restrict__ col,
                                                         int* __restrict__ degi,
                                                         int E, int npb, int chunk) {
    const int bkt = blockIdx.x & (NBKT - 1);
    const int slice = blockIdx.x >> 3;
    const int lo = bkt * npb, hi = lo + npb;
    const int e0 = slice * chunk;
    const int e1 = (e0 + chunk < E) ? e0 + chunk : E;
    for (int e = e0 + threadIdx.x; e < e1; e += 256) {
        int c = col[e];
        if (c >= lo && c < hi) atomicAdd(&degi[c], 1);
    }
}

// ================= scan1 + fused parameter prep =================
__global__ __launch_bounds__(256) void scan1_prep_kernel(
    const int* __restrict__ degi, int* __restrict__ rowptr, int* __restrict__ bsum, int n,
    int nbs,
    const float* __restrict__ b, const float* __restrict__ gamma,
    const float* __restrict__ beta, const float* __restrict__ mean,
    const float* __restrict__ var, const float* __restrict__ W0,
    const float* __restrict__ W3, const float* __restrict__ headW,
    float* __restrict__ sarr, float* __restrict__ tarr,
    float* __restrict__ Wpad, float* __restrict__ wp, float* __restrict__ c3,
    float* __restrict__ gacc, int G)
{
    const int t = threadIdx.x;
    if (blockIdx.x < nbs) {
        __shared__ int lds[256];
        const int gid = blockIdx.x * 256 + t;
        int v = (gid < n) ? degi[gid] : 0;
        lds[t] = v;
        __syncthreads();
        for (int off = 1; off < 256; off <<= 1) {
            int u = (t >= off) ? lds[t - off] : 0;
            __syncthreads();
            lds[t] += u;
            __syncthreads();
        }
        if (gid < n) rowptr[gid + 1] = lds[t];
        if (t == 255) bsum[blockIdx.x] = lds[t];
        return;
    }
    if (blockIdx.x == nbs) {
        __shared__ float ws_[H100];
        for (int idx = t; idx < 4 * H100; idx += 256) {
            float s = gamma[idx] * rsqrtf(var[idx] + BN_EPS);
            sarr[idx] = s;
            tarr[idx] = (b[idx] - mean[idx]) * s + beta[idx];
        }
        __syncthreads();
        if (t < H100) ws_[t] = sarr[3 * H100 + t] * headW[t];
        __syncthreads();
        if (t < H100) {
            float acc = 0.f;
            for (int c = 0; c < H100; ++c) acc += W3[t * H100 + c] * ws_[c];
            wp[t] = acc;
        }
        if (t == 0) {
            float acc = 0.f;
            for (int c = 0; c < H100; ++c) acc += tarr[3 * H100 + c] * headW[c];
            *c3 = acc;
        }
        return;
    }
    int idx = (blockIdx.x - nbs - 1) * 256 + t;
    if (idx < 36 * H100) {
        Wpad[idx] = (idx < 33 * H100) ? W0[idx] : 0.f;
    } else {
        int gidx = idx - 36 * H100;
        if (gidx < G) gacc[gidx] = 0.f;
    }
}

__global__ __launch_bounds__(1024) void scan2_kernel(int* __restrict__ bsum, int nb) {
    __shared__ int lds[1024];
    const int t = threadIdx.x;
    int v = (t < nb) ? bsum[t] : 0;
    lds[t] = v;
    __syncthreads();
    for (int off = 1; off < 1024; off <<= 1) {
        int u = (t >= off) ? lds[t - off] : 0;
        __syncthreads();
        lds[t] += u;
        __syncthreads();
    }
    if (t < nb) bsum[t] = lds[t] - v;   // exclusive
}

__global__ __launch_bounds__(256) void scan3_kernel(int* __restrict__ rowptr,
                                                    const int* __restrict__ bsum,
                                                    const int* __restrict__ degi,
                                                    float* __restrict__ dis,
                                                    int* __restrict__ cursor, int n) {
    const int gid = blockIdx.x * 256 + threadIdx.x;
    if (gid >= n) return;
    const int d = degi[gid];
    const int rp1 = rowptr[gid + 1] + bsum[blockIdx.x];
    rowptr[gid + 1] = rp1;
    cursor[gid] = rp1 - d;
    if (gid == 0) rowptr[0] = 0;
    dis[gid] = rsqrtf((float)(d + 1));
}

// ======== fill (bucketed by dest XCD) + xprep fused ========
__global__ __launch_bounds__(256) void fill_xprep_kernel(
    const int* __restrict__ row, const int* __restrict__ col,
    int* __restrict__ cursor, int* __restrict__ srcidx,
    int E, int npb, int chunk, int nbf,
    const float* __restrict__ x, const float* __restrict__ dis,
    float4* __restrict__ xt, int n)
{
    if (blockIdx.x < nbf) {
        const int bkt = blockIdx.x & (NBKT - 1);
        const int slice = blockIdx.x >> 3;
        const int lo = bkt * npb, hi = lo + npb;
        const int e0 = slice * chunk;
        const int e1 = (e0 + chunk < E) ? e0 + chunk : E;
        for (int e = e0 + threadIdx.x; e < e1; e += 256) {
            int c = col[e];
            if (c >= lo && c < hi) {
                int slot = atomicAdd(&cursor[c], 1);
                srcidx[slot] = row[e];
            }
        }
        return;
    }
    int t = (blockIdx.x - nbf) * 256 + threadIdx.x;
    int node = t / 9;
    if (node >= n) return;
    int q = t - node * 9;
    const float d = dis[node];
    float v[4];
    #pragma unroll
    for (int j = 0; j < 4; ++j) {
        int c = q * 4 + j;
        v[j] = (c < 33) ? x[node * 33 + c] * d : 0.f;
    }
    xt[node * 9 + q] = make_float4(v[0], v[1], v[2], v[3]);
}

// ================= gather 33-dim (flat) =================
__global__ __launch_bounds__(256) void gather33_kernel(
    const int* __restrict__ rowptr, const int* __restrict__ srcidx,
    const float4* __restrict__ xt, const float* __restrict__ dis,
    float4* __restrict__ agg0, int n)
{
    const int t = blockIdx.x * 256 + threadIdx.x;
    const int node = t / 9;
    if (node >= n) return;
    const int q = t - node * 9;

    float4 a0 = xt[node * 9 + q];
    float4 a1 = make_float4(0.f, 0.f, 0.f, 0.f);
    const int i1 = rowptr[node + 1];
    int i = rowptr[node];
    for (; i + 3 < i1; i += 4) {
        float4 v0 = xt[srcidx[i] * 9 + q];
        float4 v1 = xt[srcidx[i + 1] * 9 + q];
        float4 v2 = xt[srcidx[i + 2] * 9 + q];
        float4 v3 = xt[srcidx[i + 3] * 9 + q];
        a0.x += (v0.x + v1.x) + (v2.x + v3.x);
        a0.y += (v0.y + v1.y) + (v2.y + v3.y);
        a0.z += (v0.z + v1.z) + (v2.z + v3.z);
        a0.w += (v0.w + v1.w) + (v2.w + v3.w);
    }
    for (; i < i1; ++i) {
        float4 v0 = xt[srcidx[i] * 9 + q];
        a1.x += v0.x; a1.y += v0.y; a1.z += v0.z; a1.w += v0.w;
    }
    const float d = dis[node];
    agg0[node * 9 + q] = make_float4((a0.x + a1.x) * d, (a0.y + a1.y) * d,
                                     (a0.z + a1.z) * d, (a0.w + a1.w) * d);
}

// ========== fused layer-0 GEMM + BN/ReLU + layer-1 message GEMM ==========
// z1[i] = dis[i] * ( relu(bn(agg0[i] @ Wpad)) @ W1 );  h1 never leaves the block.
__global__ __launch_bounds__(256) void gemm_fused36_kernel(
    const float* __restrict__ agg0, const float* __restrict__ Wpad,
    const float* __restrict__ W1, const float* __restrict__ dis,
    const float* __restrict__ sarr0, const float* __restrict__ tarr0,
    float* __restrict__ z1, int n)
{
    __shared__ float Wl[50 * H100 + 32];   // 20.1 KB, reused phase A (18-row halves) / B (50-row)
    __shared__ float U[H100 * 68];         // 27.2 KB: phase A = hsT36[36][68]; phase B = h1T[100][68]
    const int tid = threadIdx.x;
    const int node0 = blockIdx.x * 64;

    // stage agg0 tile (36-dim) transposed
    for (int idx = tid; idx < 64 * 36; idx += 256) {
        int r = idx / 36;
        int k = idx - r * 36;
        int node = node0 + r;
        U[k * 68 + r] = (node < n) ? agg0[node * 36 + k] : 0.0f;
    }

    const int tx = tid & 15;
    const int ty = tid >> 4;
    float acc0[4][4] = {{0.f}};
    float acc1[4][4] = {{0.f}};

    // ---- phase A: h1pre = agg0 @ Wpad ----
    for (int p = 0; p < 2; ++p) {
        const int k0 = p * 18;
        __syncthreads();
        for (int idx = tid; idx < 18 * H100; idx += 256)
            Wl[idx] = Wpad[k0 * H100 + idx];
        __syncthreads();
        for (int kk = 0; kk < 18; ++kk) {
            const float4 a  = *reinterpret_cast<const float4*>(&U[(k0 + kk) * 68 + ty * 4]);
            const float4 w0 = *reinterpret_cast<const float4*>(&Wl[kk * H100 + tx * 4]);
            const float4 w1 = *reinterpret_cast<const float4*>(&Wl[kk * H100 + 64 + tx * 4]);
            const float av[4]  = {a.x, a.y, a.z, a.w};
            const float w0v[4] = {w0.x, w0.y, w0.z, w0.w};
            const float w1v[4] = {w1.x, w1.y, w1.z, w1.w};
            #pragma unroll
            for (int ni = 0; ni < 4; ++ni)
                #pragma unroll
                for (int ci = 0; ci < 4; ++ci) {
                    acc0[ni][ci] += av[ni] * w0v[ci];
                    acc1[ni][ci] += av[ni] * w1v[ci];
                }
        }
    }

    // ---- BN + ReLU, write h1 transposed into U ----
    __syncthreads();   // all phase-A reads of U/Wl done
    {
        const float4 s0 = *reinterpret_cast<const float4*>(&sarr0[tx * 4]);
        const float4 t0 = *reinterpret_cast<const float4*>(&tarr0[tx * 4]);
        const float s0v[4] = {s0.x, s0.y, s0.z, s0.w};
        const float t0v[4] = {t0.x, t0.y, t0.z, t0.w};
        #pragma unroll
        for (int ni = 0; ni < 4; ++ni) {
            const int r = ty * 4 + ni;
            #pragma unroll
            for (int jj = 0; jj < 4; ++jj)
                U[(tx * 4 + jj) * 68 + r] = fmaxf(acc0[ni][jj] * s0v[jj] + t0v[jj], 0.f);
        }
        if (tx < 9) {
            const float4 s1 = *reinterpret_cast<const float4*>(&sarr0[64 + tx * 4]);
            const float4 t1 = *reinterpret_cast<const float4*>(&tarr0[64 + tx * 4]);
            const float s1v[4] = {s1.x, s1.y, s1.z, s1.w};
            const float t1v[4] = {t1.x, t1.y, t1.z, t1.w};
            #pragma unroll
            for (int ni = 0; ni < 4; ++ni) {
                const int r = ty * 4 + ni;
                #pragma unroll
                for (int jj = 0; jj < 4; ++jj)
                    U[(64 + tx * 4 + jj) * 68 + r] = fmaxf(acc1[ni][jj] * s1v[jj] + t1v[jj], 0.f);
            }
        }
    }

    // ---- phase B: z1 = (h1 @ W1) * dis ----
    float bcc0[4][4] = {{0.f}};
    float bcc1[4][4] = {{0.f}};
    for (int p = 0; p < 2; ++p) {
        const int k0 = p * 50;
        __syncthreads();
        for (int idx = tid; idx < 50 * H100; idx += 256)
            Wl[idx] = W1[k0 * H100 + idx];
        __syncthreads();
        for (int kk = 0; kk < 50; ++kk) {
            const float4 a  = *reinterpret_cast<const float4*>(&U[(k0 + kk) * 68 + ty * 4]);
            const float4 w0 = *reinterpret_cast<const float4*>(&Wl[kk * H100 + tx * 4]);
            const float4 w1 = *reinterpret_cast<const float4*>(&Wl[kk * H100 + 64 + tx * 4]);
            const float av[4]  = {a.x, a.y, a.z, a.w};
            const float w0v[4] = {w0.x, w0.y, w0.z, w0.w};
            const float w1v[4] = {w1.x, w1.y, w1.z, w1.w};
            #pragma unroll
            for (int ni = 0; ni < 4; ++ni)
                #pragma unroll
                for (int ci = 0; ci < 4; ++ci) {
                    bcc0[ni][ci] += av[ni] * w0v[ci];
                    bcc1[ni][ci] += av[ni] * w1v[ci];
                }
        }
    }

    #pragma unroll
    for (int ni = 0; ni < 4; ++ni) {
        const int node = node0 + ty * 4 + ni;
        if (node >= n) continue;
        const float d = dis[node];
        float4 o0 = make_float4(bcc0[ni][0] * d, bcc0[ni][1] * d, bcc0[ni][2] * d, bcc0[ni][3] * d);
        *reinterpret_cast<float4*>(&z1[node * H100 + tx * 4]) = o0;
        if (tx < 9) {
            float4 o1 = make_float4(bcc1[ni][0] * d, bcc1[ni][1] * d, bcc1[ni][2] * d, bcc1[ni][3] * d);
            *reinterpret_cast<float4*>(&z1[node * H100 + 64 + tx * 4]) = o1;
        }
    }
}

// ========== fused gather + BN/ReLU + message GEMM ==========
// z2[i] = dis[i] * ( relu(bn(dis[i]*(self + sum z1[src]))) @ W2 ); h2 stays in LDS.
// 512 threads: 20 groups x 25 threads, 1 node per group.
__global__ __launch_bounds__(512) void gather_gemm_kernel(
    const int* __restrict__ rowptr, const int* __restrict__ srcidx,
    const float4* __restrict__ z4, const float* __restrict__ dis,
    const float* __restrict__ sarr, const float* __restrict__ tarr,
    const float* __restrict__ W2, float* __restrict__ z2, int n)
{
    __shared__ float Wl[H100 * 104];    // 41.6 KB, padded stride 104
    __shared__ float hrow[20 * 104];    // 8.3 KB
    const int tid = threadIdx.x;

    for (int idx = tid; idx < H100 * 104; idx += 512) {
        int r = idx / 104;
        int c = idx - r * 104;
        Wl[idx] = (c < H100) ? W2[r * H100 + c] : 0.f;
    }

    const int g = tid / 25;
    const int q = tid - g * 25;
    const bool act = (g < 20);
    const int node = blockIdx.x * 20 + g;
    const bool valid = act && (node < n);

    float4 a0 = make_float4(0.f, 0.f, 0.f, 0.f);
    float4 a1 = make_float4(0.f, 0.f, 0.f, 0.f);
    float dn = 0.f;
    if (valid) {
        a0 = z4[node * 25 + q];             // self-loop (already *dis)
        dn = dis[node];
        const int i1 = rowptr[node + 1];
        int i = rowptr[node];
        for (; i + 7 < i1; i += 8) {
            float4 v0 = z4[srcidx[i] * 25 + q];
            float4 v1 = z4[srcidx[i + 1] * 25 + q];
            float4 v2 = z4[srcidx[i + 2] * 25 + q];
            float4 v3 = z4[srcidx[i + 3] * 25 + q];
            float4 v4 = z4[srcidx[i + 4] * 25 + q];
            float4 v5 = z4[srcidx[i + 5] * 25 + q];
            float4 v6 = z4[srcidx[i + 6] * 25 + q];
            float4 v7 = z4[srcidx[i + 7] * 25 + q];
            a0.x += (v0.x + v1.x) + (v2.x + v3.x); a1.x += (v4.x + v5.x) + (v6.x + v7.x);
            a0.y += (v0.y + v1.y) + (v2.y + v3.y); a1.y += (v4.y + v5.y) + (v6.y + v7.y);
            a0.z += (v0.z + v1.z) + (v2.z + v3.z); a1.z += (v4.z + v5.z) + (v6.z + v7.z);
            a0.w += (v0.w + v1.w) + (v2.w + v3.w); a1.w += (v4.w + v5.w) + (v6.w + v7.w);
        }
        for (; i + 3 < i1; i += 4) {
            float4 v0 = z4[srcidx[i] * 25 + q];
            float4 v1 = z4[srcidx[i + 1] * 25 + q];
            float4 v2 = z4[srcidx[i + 2] * 25 + q];
            float4 v3 = z4[srcidx[i + 3] * 25 + q];
            a0.x += (v0.x + v1.x) + (v2.x + v3.x);
            a0.y += (v0.y + v1.y) + (v2.y + v3.y);
            a0.z += (v0.z + v1.z) + (v2.z + v3.z);
            a0.w += (v0.w + v1.w) + (v2.w + v3.w);
        }
        for (; i < i1; ++i) {
            float4 v0 = z4[srcidx[i] * 25 + q];
            a0.x += v0.x; a0.y += v0.y; a0.z += v0.z; a0.w += v0.w;
        }
    }

    if (act) {
        const float4 s  = *reinterpret_cast<const float4*>(&sarr[q * 4]);
        const float4 tt = *reinterpret_cast<const float4*>(&tarr[q * 4]);
        float* hr = &hrow[g * 104 + q * 4];
        hr[0] = fmaxf((a0.x + a1.x) * dn * s.x + tt.x, 0.f);
        hr[1] = fmaxf((a0.y + a1.y) * dn * s.y + tt.y, 0.f);
        hr[2] = fmaxf((a0.z + a1.z) * dn * s.z + tt.z, 0.f);
        hr[3] = fmaxf((a0.w + a1.w) * dn * s.w + tt.w, 0.f);
    }
    __syncthreads();   // hrow + Wl ready

    if (valid) {
        float z0 = 0.f, zz1 = 0.f, z2v = 0.f, z3 = 0.f;
        const float* hr = &hrow[g * 104];
        #pragma unroll 5
        for (int cq = 0; cq < 25; ++cq) {
            const float4 h = *reinterpret_cast<const float4*>(&hr[cq * 4]);
            const float* wr = &Wl[(cq * 4) * 104 + q * 4];
            const float4 w0 = *reinterpret_cast<const float4*>(wr);
            const float4 w1 = *reinterpret_cast<const float4*>(wr + 104);
            const float4 w2v = *reinterpret_cast<const float4*>(wr + 208);
            const float4 w3 = *reinterpret_cast<const float4*>(wr + 312);
            z0  += h.x * w0.x + h.y * w1.x + h.z * w2v.x + h.w * w3.x;
            zz1 += h.x * w0.y + h.y * w1.y + h.z * w2v.y + h.w * w3.y;
            z2v += h.x * w0.z + h.y * w1.z + h.z * w2v.z + h.w * w3.z;
            z3  += h.x * w0.w + h.y * w1.w + h.z * w2v.w + h.w * w3.w;
        }
        *reinterpret_cast<float4*>(&z2[node * H100 + q * 4]) =
            make_float4(z0 * dn, zz1 * dn, z2v * dn, z3 * dn);
    }
}

// ================= gather 100-dim MODE1 (rank-1 head fused) =================
__global__ __launch_bounds__(256) void gather100_head_kernel(
    const int* __restrict__ rowptr, const int* __restrict__ srcidx,
    const float4* __restrict__ z4, const float* __restrict__ dis,
    const float* __restrict__ sarr, const float* __restrict__ tarr,
    const float* __restrict__ wp, float* __restrict__ y, int n)
{
    const int tid = threadIdx.x;
    const int node = blockIdx.x * 10 + tid / 25;
    const int q = tid % 25;
    const bool valid = (tid < 250) && (node < n);

    float4 a0 = make_float4(0.f, 0.f, 0.f, 0.f);
    float4 a1 = make_float4(0.f, 0.f, 0.f, 0.f);
    float dn = 0.f;
    if (valid) {
        a0 = z4[node * 25 + q];
        dn = dis[node];
        const int i1 = rowptr[node + 1];
        int i = rowptr[node];
        for (; i + 7 < i1; i += 8) {
            float4 v0 = z4[srcidx[i] * 25 + q];
            float4 v1 = z4[srcidx[i + 1] * 25 + q];
            float4 v2 = z4[srcidx[i + 2] * 25 + q];
            float4 v3 = z4[srcidx[i + 3] * 25 + q];
            float4 v4 = z4[srcidx[i + 4] * 25 + q];
            float4 v5 = z4[srcidx[i + 5] * 25 + q];
            float4 v6 = z4[srcidx[i + 6] * 25 + q];
            float4 v7 = z4[srcidx[i + 7] * 25 + q];
            a0.x += (v0.x + v1.x) + (v2.x + v3.x); a1.x += (v4.x + v5.x) + (v6.x + v7.x);
            a0.y += (v0.y + v1.y) + (v2.y + v3.y); a1.y += (v4.y + v5.y) + (v6.y + v7.y);
            a0.z += (v0.z + v1.z) + (v2.z + v3.z); a1.z += (v4.z + v5.z) + (v6.z + v7.z);
            a0.w += (v0.w + v1.w) + (v2.w + v3.w); a1.w += (v4.w + v5.w) + (v6.w + v7.w);
        }
        for (; i + 3 < i1; i += 4) {
            float4 v0 = z4[srcidx[i] * 25 + q];
            float4 v1 = z4[srcidx[i + 1] * 25 + q];
            float4 v2 = z4[srcidx[i + 2] * 25 + q];
            float4 v3 = z4[srcidx[i + 3] * 25 + q];
            a0.x += (v0.x + v1.x) + (v2.x + v3.x);
            a0.y += (v0.y + v1.y) + (v2.y + v3.y);
            a0.z += (v0.z + v1.z) + (v2.z + v3.z);
            a0.w += (v0.w + v1.w) + (v2.w + v3.w);
        }
        for (; i < i1; ++i) {
            float4 v0 = z4[srcidx[i] * 25 + q];
            a0.x += v0.x; a0.y += v0.y; a0.z += v0.z; a0.w += v0.w;
        }
    }

    const float4 s  = *reinterpret_cast<const float4*>(&sarr[q * 4]);
    const float4 tt = *reinterpret_cast<const float4*>(&tarr[q * 4]);
    const float4 w  = *reinterpret_cast<const float4*>(&wp[q * 4]);
    float hv0 = fmaxf((a0.x + a1.x) * dn * s.x + tt.x, 0.f);
    float hv1 = fmaxf((a0.y + a1.y) * dn * s.y + tt.y, 0.f);
    float hv2 = fmaxf((a0.z + a1.z) * dn * s.z + tt.z, 0.f);
    float hv3 = fmaxf((a0.w + a1.w) * dn * s.w + tt.w, 0.f);
    float partial = hv0 * w.x + hv1 * w.y + hv2 * w.z + hv3 * w.w;

    __shared__ float red[256];
    red[tid] = valid ? partial : 0.f;
    __syncthreads();
    if (valid && q == 0) {
        float sum = 0.f;
        #pragma unroll
        for (int j = 0; j < 25; ++j) sum += red[tid + j];
        y[node] = sum * dn;
    }
}

// ================= scalar gather (layer 3 collapsed) + pool =================
__global__ __launch_bounds__(256) void gather_scalar_kernel(
    const int* __restrict__ rowptr, const int* __restrict__ srcidx,
    const float* __restrict__ y, const float* __restrict__ dis,
    const float* __restrict__ c3, const int* __restrict__ batch,
    float* __restrict__ gacc, int n)
{
    const int node = blockIdx.x * 256 + threadIdx.x;
    if (node >= n) return;
    float acc = y[node];
    float accb = 0.f;
    const int i1 = rowptr[node + 1];
    int i = rowptr[node];
    for (; i + 7 < i1; i += 8) {
        acc  += (y[srcidx[i]]     + y[srcidx[i + 1]]) + (y[srcidx[i + 2]] + y[srcidx[i + 3]]);
        accb += (y[srcidx[i + 4]] + y[srcidx[i + 5]]) + (y[srcidx[i + 6]] + y[srcidx[i + 7]]);
    }
    for (; i + 3 < i1; i += 4)
        acc += (y[srcidx[i]] + y[srcidx[i + 1]]) + (y[srcidx[i + 2]] + y[srcidx[i + 3]]);
    for (; i < i1; ++i) acc += y[srcidx[i]];
    unsafeAtomicAdd(&gacc[batch[node]], dis[node] * (acc + accb) + c3[0]);
}

__global__ __launch_bounds__(256) void finish_kernel(const float* __restrict__ gacc,
                                                     const float* __restrict__ hb,
                                                     float* __restrict__ out, int G) {
    int g = blockIdx.x * 256 + threadIdx.x;
    if (g >= G) return;
    float o = gacc[g] + hb[0];
    out[g] = (o >= 0.f) ? o : 0.1f * o;
}

extern "C" void kernel_launch(void* const* d_in, const int* in_sizes, int n_in,
                              void* d_out, int out_size, void* d_ws, size_t ws_size,
                              hipStream_t stream) {
    const float* x       = (const float*)d_in[0];
    const int*   ei      = (const int*)d_in[1];
    const int*   batch   = (const int*)d_in[2];
    const float* W0      = (const float*)d_in[3];
    const float* Ws      = (const float*)d_in[4];
    const float* biases  = (const float*)d_in[5];
    const float* gamma   = (const float*)d_in[6];
    const float* beta    = (const float*)d_in[7];
    const float* bn_mean = (const float*)d_in[8];
    const float* bn_var  = (const float*)d_in[9];
    const float* headW   = (const float*)d_in[10];
    const float* headb   = (const float*)d_in[11];
    float* out = (float*)d_out;

    const int N = in_sizes[2];
    const int E = in_sizes[1] / 2;
    const int G = out_size;
    const int* row  = ei;
    const int* colp = ei + E;

    char* ws = (char*)d_ws;
    size_t off = 0;
    auto carve = [&](size_t bytes) -> void* {
        void* p = (void*)(ws + off);
        off += (bytes + 255) & ~(size_t)255;
        return p;
    };
    float*  dis    = (float*)carve((size_t)N * 4);
    float4* xt     = (float4*)carve((size_t)N * 9 * 16);
    float4* agg0   = (float4*)carve((size_t)N * 9 * 16);
    float*  bufA   = (float*)carve((size_t)N * H100 * 4);   // z1
    float*  bufB   = (float*)carve((size_t)N * H100 * 4);   // z2
    float*  y      = (float*)carve((size_t)N * 4);
    int*    degi   = (int*)carve((size_t)N * 4);
    int*    rowptr = (int*)carve((size_t)(N + 1) * 4);
    int*    cursor = (int*)carve((size_t)N * 4);
    int*    srcidx = (int*)carve((size_t)E * 4);
    int*    bsum   = (int*)carve(1024 * 4);
    float*  sarr   = (float*)carve(4 * H100 * 4);
    float*  tarr   = (float*)carve(4 * H100 * 4);
    float*  wp     = (float*)carve(H100 * 4);
    float*  c3     = (float*)carve(256);
    float*  Wpad   = (float*)carve(36 * H100 * 4);
    float*  gacc   = (float*)carve((size_t)G * 4);

    const int nb_n  = (N + 255) / 256;
    const int nb_g  = (N + 63) / 64;
    const int nb_9  = (N * 9 + 255) / 256;
    const int nb_ga = (N + 9) / 10;
    const int nb_gg = (N + 19) / 20;
    const int npb   = (N + NBKT - 1) / NBKT;
    const int chunk = (E + NSLICE - 1) / NSLICE;
    const int nb_bkt = NBKT * NSLICE;
    const int nb_pad = (36 * H100 + G + 255) / 256;

    // ---- CSR + params ----
    hipMemsetAsync(degi, 0, (size_t)N * 4, stream);
    deg_bucket_kernel<<<nb_bkt, 256, 0, stream>>>(colp, degi, E, npb, chunk);
    scan1_prep_kernel<<<nb_n + 1 + nb_pad, 256, 0, stream>>>(
        degi, rowptr, bsum, N, nb_n,
        biases, gamma, beta, bn_mean, bn_var, W0,
        Ws + 2 * H100 * H100, headW, sarr, tarr, Wpad, wp, c3, gacc, G);
    scan2_kernel<<<1, 1024, 0, stream>>>(bsum, nb_n);
    scan3_kernel<<<nb_n, 256, 0, stream>>>(rowptr, bsum, degi, dis, cursor, N);
    fill_xprep_kernel<<<nb_bkt + nb_9, 256, 0, stream>>>(row, colp, cursor, srcidx,
                                                         E, npb, chunk, nb_bkt,
                                                         x, dis, xt, N);

    // ---- layer 0 aggregate, then fused GEMM(36->100)+BN+ReLU+GEMM(100->100) ----
    gather33_kernel<<<nb_9, 256, 0, stream>>>(rowptr, srcidx, xt, dis, agg0, N);
    gemm_fused36_kernel<<<nb_g, 256, 0, stream>>>((const float*)agg0, Wpad, Ws, dis,
                                                  sarr, tarr, bufA, N);           // z1

    // ---- layer 1 gather + BN/ReLU + layer-2 message GEMM (fused) ----
    gather_gemm_kernel<<<nb_gg, 512, 0, stream>>>(rowptr, srcidx, (const float4*)bufA, dis,
                                                  sarr + H100, tarr + H100,
                                                  Ws + H100 * H100, bufB, N);     // z2

    // ---- layer 2 gather + rank-1 head projection ----
    gather100_head_kernel<<<nb_ga, 256, 0, stream>>>(rowptr, srcidx, (const float4*)bufB, dis,
                                                     sarr + 2 * H100, tarr + 2 * H100, wp, y, N);

    // ---- layer 3 collapsed to scalar gather + pool ----
    gather_scalar_kernel<<<nb_n, 256, 0, stream>>>(rowptr, srcidx, y, dis, c3, batch, gacc, N);
    finish_kernel<<<(G + 255) / 256, 256, 0, stream>>>(gacc, headb, out, G);
}